// Round 1
// baseline (586.985 us; speedup 1.0000x reference)
//
#include <hip/hip_runtime.h>
#include <hip/hip_bf16.h>

// Sizes (fixed by the problem, N/E/G derived from in_sizes at launch)
#define FH 96      // F == H == 96
#define GU 32      // U
#define GA 16      // A
#define NG 64      // G

// ---------------------------------------------------------------------------
// Kernel 1: in-degree count (int atomics, exact)
__global__ void count_deg_k(const int* __restrict__ dst, int* __restrict__ deg, int E) {
    int e = blockIdx.x * blockDim.x + threadIdx.x;
    if (e < E) atomicAdd(&deg[dst[e]], 1);
}

// Kernel 2: dis = rsqrt(deg + 1)
__global__ void dis_k(const int* __restrict__ deg, float* __restrict__ dis, int n) {
    int i = blockIdx.x * blockDim.x + threadIdx.x;
    if (i < n) dis[i] = rsqrtf((float)deg[i] + 1.0f);
}

// Kernel 3: single-block exclusive prefix scan of deg -> rowstart, cursor
__global__ __launch_bounds__(1024) void scan_k(const int* __restrict__ deg,
                                               int* __restrict__ rowstart,
                                               int* __restrict__ cursor, int n) {
    __shared__ int sums[1024];
    const int T = 1024;
    int t = threadIdx.x;
    int chunk = (n + T - 1) / T;
    int beg = t * chunk;
    int end = min(beg + chunk, n);
    int s = 0;
    for (int i = beg; i < end; i++) s += deg[i];
    sums[t] = s;
    __syncthreads();
    // Hillis-Steele inclusive scan
    for (int off = 1; off < T; off <<= 1) {
        int v = 0;
        if (t >= off) v = sums[t - off];
        __syncthreads();
        if (t >= off) sums[t] += v;
        __syncthreads();
    }
    int run = (t == 0) ? 0 : sums[t - 1];
    for (int i = beg; i < end; i++) {
        rowstart[i] = run;
        cursor[i] = run;
        run += deg[i];
    }
    if (t == T - 1) rowstart[n] = run;
}

// Kernel 4: fill CSR (src ids per dst)
__global__ void fill_k(const int* __restrict__ src, const int* __restrict__ dst,
                       int* __restrict__ cursor, int* __restrict__ csr, int E) {
    int e = blockIdx.x * blockDim.x + threadIdx.x;
    if (e < E) {
        int pos = atomicAdd(&cursor[dst[e]], 1);
        csr[pos] = src[e];
    }
}

// Kernel 5: Y[n][f] = sum_k X[n][k] * W[k][f]   (no bias)
// block = (128, 2); each block does 16 rows; thread f computes 8 rows' col f.
__global__ __launch_bounds__(256) void gemm96_k(const float* __restrict__ X,
                                                const float* __restrict__ W,
                                                float* __restrict__ Y, int nrows) {
    __shared__ float Ws[FH][100];   // padded
    __shared__ float Xs[16][100];   // padded (400B row stride, 16B aligned)
    int t = threadIdx.y * 128 + threadIdx.x;
    // stage W
    for (int i = t; i < FH * FH; i += 256) Ws[i / FH][i % FH] = W[i];
    // stage X tile
    int base = blockIdx.x * 16;
    for (int i = t; i < 16 * FH; i += 256) {
        int r = i / FH, c = i % FH;
        int node = base + r;
        Xs[r][c] = (node < nrows) ? X[node * FH + c] : 0.0f;
    }
    __syncthreads();

    int fc = min((int)threadIdx.x, FH - 1);
    int nb = threadIdx.y * 8;
    float acc[8] = {0, 0, 0, 0, 0, 0, 0, 0};
    for (int kb = 0; kb < FH / 4; kb++) {
        int k = kb * 4;
        float w0 = Ws[k][fc], w1 = Ws[k + 1][fc], w2 = Ws[k + 2][fc], w3 = Ws[k + 3][fc];
#pragma unroll
        for (int i = 0; i < 8; i++) {
            const float4 xv = *(const float4*)&Xs[nb + i][k];
            acc[i] += xv.x * w0 + xv.y * w1 + xv.z * w2 + xv.w * w3;
        }
    }
    if (threadIdx.x < FH) {
#pragma unroll
        for (int i = 0; i < 8; i++) {
            int node = base + nb + i;
            if (node < nrows) Y[node * FH + threadIdx.x] = acc[i];
        }
    }
}

// Kernel 6: fused aggregate + self-loop + bias + relu
// hOut[n][f] = relu( dis[n]*sum_e hX[src_e][f]*dis[src_e] + hX[n][f]*dis[n]^2 + b[f] )
__global__ void gather_k(const float* __restrict__ hX, const float* __restrict__ dis,
                         const int* __restrict__ rowstart, const int* __restrict__ deg,
                         const int* __restrict__ csr, const float* __restrict__ bias,
                         float* __restrict__ hOut, int n) {
    int idx = blockIdx.x * blockDim.x + threadIdx.x;
    if (idx >= n * FH) return;
    int node = idx / FH;
    int f = idx - node * FH;
    int s = rowstart[node];
    int d = deg[node];
    float sum = 0.0f;
    for (int p = 0; p < d; p++) {
        int sc = csr[s + p];
        sum += hX[sc * FH + f] * dis[sc];
    }
    float dn = dis[node];
    float v = sum * dn + hX[idx] * dn * dn + bias[f];
    hOut[idx] = fmaxf(v, 0.0f);
}

// Kernel 7: pooling — per-block LDS accumulation then global atomics
__global__ __launch_bounds__(256) void pool_k(const float* __restrict__ h,
                                              const int* __restrict__ batch,
                                              float* __restrict__ pooled,
                                              float* __restrict__ cnt, int n) {
    __shared__ float lp[NG * FH];
    __shared__ float lc[NG];
    const int CH = 256;
    int base = blockIdx.x * CH;
    for (int i = threadIdx.x; i < NG * FH; i += 256) lp[i] = 0.0f;
    for (int i = threadIdx.x; i < NG; i += 256) lc[i] = 0.0f;
    __syncthreads();
    for (int i = threadIdx.x; i < CH * FH; i += 256) {
        int r = i / FH, f = i - r * FH;
        int node = base + r;
        if (node < n) {
            int g = batch[node];
            atomicAdd(&lp[g * FH + f], h[node * FH + f]);
            if (f == 0) atomicAdd(&lc[g], 1.0f);
        }
    }
    __syncthreads();
    for (int i = threadIdx.x; i < NG * FH; i += 256)
        if (lp[i] != 0.0f) atomicAdd(&pooled[i], lp[i]);
    if (threadIdx.x < NG)
        if (lc[threadIdx.x] != 0.0f) atomicAdd(&cnt[threadIdx.x], lc[threadIdx.x]);
}

// Kernel 8: heads — one block per graph
__global__ __launch_bounds__(128) void head_k(const float* __restrict__ pooled,
                                              const float* __restrict__ cnt,
                                              const float* __restrict__ u,
                                              const float* __restrict__ aW1, const float* __restrict__ ab1,
                                              const float* __restrict__ aW2, const float* __restrict__ ab2,
                                              const float* __restrict__ cW1, const float* __restrict__ cb1,
                                              const float* __restrict__ cW2, const float* __restrict__ cb2,
                                              float* __restrict__ out, int G) {
    int g = blockIdx.x;
    int t = threadIdx.x;
    __shared__ float comb[FH + GU];
    __shared__ float hidA[FH];
    __shared__ float hidC[FH];
    __shared__ float tmp[FH];
    float c = fmaxf(cnt[g], 1.0f);
    if (t < FH) comb[t] = pooled[g * FH + t] / c;
    else if (t < FH + GU) comb[t] = u[g * GU + (t - FH)];
    __syncthreads();
    if (t < FH) {
        float a = ab1[t], cc = cb1[t];
        for (int k = 0; k < FH + GU; k++) {
            float cv = comb[k];
            a += cv * aW1[k * FH + t];
            cc += cv * cW1[k * FH + t];
        }
        hidA[t] = fmaxf(a, 0.0f);
        hidC[t] = fmaxf(cc, 0.0f);
    }
    __syncthreads();
    if (t < GA) {
        float a = ab2[t];
        for (int j = 0; j < FH; j++) a += hidA[j] * aW2[j * GA + t];
        out[g * GA + t] = a;
    }
    if (t >= 32 && t < 32 + FH) tmp[t - 32] = hidC[t - 32] * cW2[t - 32];
    __syncthreads();
    if (t == 0) {
        float v = cb2[0];
        for (int j = 0; j < FH; j++) v += tmp[j];
        out[G * GA + g] = v;
    }
}

extern "C" void kernel_launch(void* const* d_in, const int* in_sizes, int n_in,
                              void* d_out, int out_size, void* d_ws, size_t ws_size,
                              hipStream_t stream) {
    const float* x   = (const float*)d_in[0];
    const int*   ei  = (const int*)d_in[1];
    const int*   bat = (const int*)d_in[2];
    const float* u   = (const float*)d_in[3];
    const float* W1  = (const float*)d_in[4];
    const float* b1  = (const float*)d_in[5];
    const float* W2  = (const float*)d_in[6];
    const float* b2  = (const float*)d_in[7];
    const float* aW1 = (const float*)d_in[8];
    const float* ab1 = (const float*)d_in[9];
    const float* aW2 = (const float*)d_in[10];
    const float* ab2 = (const float*)d_in[11];
    const float* cW1 = (const float*)d_in[12];
    const float* cb1 = (const float*)d_in[13];
    const float* cW2 = (const float*)d_in[14];
    const float* cb2 = (const float*)d_in[15];
    float* out = (float*)d_out;

    const int N = in_sizes[0] / FH;
    const int E = in_sizes[1] / 2;
    const int G = in_sizes[3] / GU;

    const int* src = ei;
    const int* dst = ei + E;

    // Workspace layout (4-byte units, 64-elem aligned blocks)
    float* ws = (float*)d_ws;
    size_t o = 0;
    int*   degI     = (int*)(ws + o);   o += 50048;            // N ints
    float* pooled   = ws + o;           o += NG * FH;          // 6144
    float* cnt      = ws + o;           o += 64;
    size_t zero_elems = o;                                     // zero [0, o)
    float* dis      = ws + o;           o += 50048;
    int*   rowstart = (int*)(ws + o);   o += 50048;            // N+1
    int*   cursor   = (int*)(ws + o);   o += 50048;
    int*   csr      = (int*)(ws + o);   o += 800000;           // E
    float* hX       = ws + o;           o += (size_t)N * FH;
    float* hOut     = ws + o;           o += (size_t)N * FH;
    (void)ws_size;

    hipMemsetAsync(d_ws, 0, zero_elems * sizeof(float), stream);

    int gridE = (E + 255) / 256;
    int gridN = (N + 255) / 256;
    int gridNF = (N * FH + 255) / 256;
    int gridGemm = (N + 15) / 16;

    count_deg_k<<<gridE, 256, 0, stream>>>(dst, degI, E);
    dis_k<<<gridN, 256, 0, stream>>>(degI, dis, N);
    scan_k<<<1, 1024, 0, stream>>>(degI, rowstart, cursor, N);
    fill_k<<<gridE, 256, 0, stream>>>(src, dst, cursor, csr, E);

    // Layer 1
    gemm96_k<<<gridGemm, dim3(128, 2), 0, stream>>>(x, W1, hX, N);
    gather_k<<<gridNF, 256, 0, stream>>>(hX, dis, rowstart, degI, csr, b1, hOut, N);
    // Layer 2
    gemm96_k<<<gridGemm, dim3(128, 2), 0, stream>>>(hOut, W2, hX, N);
    gather_k<<<gridNF, 256, 0, stream>>>(hX, dis, rowstart, degI, csr, b2, hOut, N);

    // Pool + heads
    pool_k<<<gridN, 256, 0, stream>>>(hOut, bat, pooled, cnt, N);
    head_k<<<G, 128, 0, stream>>>(pooled, cnt, u, aW1, ab1, aW2, ab2,
                                  cW1, cb1, cW2, cb2, out, G);
}

// Round 2
// 440.438 us; speedup vs baseline: 1.3327x; 1.3327x over previous
//
#include <hip/hip_runtime.h>
#include <hip/hip_bf16.h>

// Sizes (fixed by the problem, N/E/G derived from in_sizes at launch)
#define FH 96      // F == H == 96
#define GU 32      // U
#define GA 16      // A
#define NG 64      // G

// ---------------------------------------------------------------------------
// Kernel 1: in-degree count (int atomics, exact)
__global__ void count_deg_k(const int* __restrict__ dst, int* __restrict__ deg, int E) {
    int e = blockIdx.x * blockDim.x + threadIdx.x;
    if (e < E) atomicAdd(&deg[dst[e]], 1);
}

// Kernel 2: dis = rsqrt(deg + 1)
__global__ void dis_k(const int* __restrict__ deg, float* __restrict__ dis, int n) {
    int i = blockIdx.x * blockDim.x + threadIdx.x;
    if (i < n) dis[i] = rsqrtf((float)deg[i] + 1.0f);
}

// Kernel 3: single-block exclusive prefix scan of deg -> rowstart, cursor
__global__ __launch_bounds__(1024) void scan_k(const int* __restrict__ deg,
                                               int* __restrict__ rowstart,
                                               int* __restrict__ cursor, int n) {
    __shared__ int sums[1024];
    const int T = 1024;
    int t = threadIdx.x;
    int chunk = (n + T - 1) / T;
    int beg = t * chunk;
    int end = min(beg + chunk, n);
    int s = 0;
    for (int i = beg; i < end; i++) s += deg[i];
    sums[t] = s;
    __syncthreads();
    // Hillis-Steele inclusive scan
    for (int off = 1; off < T; off <<= 1) {
        int v = 0;
        if (t >= off) v = sums[t - off];
        __syncthreads();
        if (t >= off) sums[t] += v;
        __syncthreads();
    }
    int run = (t == 0) ? 0 : sums[t - 1];
    for (int i = beg; i < end; i++) {
        rowstart[i] = run;
        cursor[i] = run;
        run += deg[i];
    }
    if (t == T - 1) rowstart[n] = run;
}

// Kernel 4: fill CSR (src ids per dst)
__global__ void fill_k(const int* __restrict__ src, const int* __restrict__ dst,
                       int* __restrict__ cursor, int* __restrict__ csr, int E) {
    int e = blockIdx.x * blockDim.x + threadIdx.x;
    if (e < E) {
        int pos = atomicAdd(&cursor[dst[e]], 1);
        csr[pos] = src[e];
    }
}

// Kernel 5: Y[n][f] = (sum_k X[n][k] * W[k][f]) * scale[n]   (no bias)
// block = (128, 2); 32 rows per block; thread (fc, ty) computes 16 rows' col fc.
__global__ __launch_bounds__(256) void gemm96s_k(const float* __restrict__ X,
                                                 const float* __restrict__ W,
                                                 const float* __restrict__ scale,
                                                 float* __restrict__ Y, int nrows) {
    __shared__ float Ws[FH][100];   // padded
    __shared__ float Xs[32][100];   // padded
    int t = threadIdx.y * 128 + threadIdx.x;
    // stage W
    for (int i = t; i < FH * FH; i += 256) Ws[i / FH][i % FH] = W[i];
    // stage X tile
    int base = blockIdx.x * 32;
    for (int i = t; i < 32 * FH; i += 256) {
        int r = i / FH, c = i % FH;
        int node = base + r;
        Xs[r][c] = (node < nrows) ? X[node * FH + c] : 0.0f;
    }
    __syncthreads();

    int fc = min((int)threadIdx.x, FH - 1);
    int nb = threadIdx.y * 16;
    float acc[16];
#pragma unroll
    for (int i = 0; i < 16; i++) acc[i] = 0.0f;
    for (int kb = 0; kb < FH / 4; kb++) {
        int k = kb * 4;
        float w0 = Ws[k][fc], w1 = Ws[k + 1][fc], w2 = Ws[k + 2][fc], w3 = Ws[k + 3][fc];
#pragma unroll
        for (int i = 0; i < 16; i++) {
            const float4 xv = *(const float4*)&Xs[nb + i][k];
            acc[i] += xv.x * w0 + xv.y * w1 + xv.z * w2 + xv.w * w3;
        }
    }
    if (threadIdx.x < FH) {
#pragma unroll
        for (int i = 0; i < 16; i++) {
            int node = base + nb + i;
            if (node < nrows) Y[node * FH + threadIdx.x] = acc[i] * scale[node];
        }
    }
}

// Kernel 6: fused aggregate + self-loop + bias + relu, float4 per thread.
// hXs is pre-scaled: hXs[n][f] = (X@W)[n][f] * dis[n]
// hOut[n][f] = relu( dis[n] * ( sum_e hXs[src_e][f] + hXs[n][f] ) + b[f] )
__global__ void gather4_k(const float* __restrict__ hXs, const float* __restrict__ dis,
                          const int* __restrict__ rowstart,
                          const int* __restrict__ csr, const float* __restrict__ bias,
                          float* __restrict__ hOut, int n) {
    int idx = blockIdx.x * blockDim.x + threadIdx.x;
    if (idx >= n * 24) return;
    int node = idx / 24;
    int fq = idx - node * 24;
    int f4 = fq * 4;
    int s = rowstart[node];
    int e = rowstart[node + 1];

    float4 acc = *(const float4*)&hXs[node * FH + f4];   // self term (pre-scaled)
    int p = s;
    for (; p + 4 <= e; p += 4) {
        int i0 = csr[p], i1 = csr[p + 1], i2 = csr[p + 2], i3 = csr[p + 3];
        float4 a = *(const float4*)&hXs[i0 * FH + f4];
        float4 b = *(const float4*)&hXs[i1 * FH + f4];
        float4 c = *(const float4*)&hXs[i2 * FH + f4];
        float4 d = *(const float4*)&hXs[i3 * FH + f4];
        acc.x += (a.x + b.x) + (c.x + d.x);
        acc.y += (a.y + b.y) + (c.y + d.y);
        acc.z += (a.z + b.z) + (c.z + d.z);
        acc.w += (a.w + b.w) + (c.w + d.w);
    }
    for (; p < e; p++) {
        int i0 = csr[p];
        float4 a = *(const float4*)&hXs[i0 * FH + f4];
        acc.x += a.x; acc.y += a.y; acc.z += a.z; acc.w += a.w;
    }
    float dn = dis[node];
    const float4 bv = *(const float4*)&bias[f4];
    float4 o;
    o.x = fmaxf(acc.x * dn + bv.x, 0.0f);
    o.y = fmaxf(acc.y * dn + bv.y, 0.0f);
    o.z = fmaxf(acc.z * dn + bv.z, 0.0f);
    o.w = fmaxf(acc.w * dn + bv.w, 0.0f);
    *(float4*)&hOut[node * FH + f4] = o;
}

// Kernel 7: pooling — per-block LDS accumulation then global atomics
__global__ __launch_bounds__(256) void pool_k(const float* __restrict__ h,
                                              const int* __restrict__ batch,
                                              float* __restrict__ pooled,
                                              float* __restrict__ cnt, int n) {
    __shared__ float lp[NG * FH];
    __shared__ float lc[NG];
    const int CH = 256;
    int base = blockIdx.x * CH;
    for (int i = threadIdx.x; i < NG * FH; i += 256) lp[i] = 0.0f;
    for (int i = threadIdx.x; i < NG; i += 256) lc[i] = 0.0f;
    __syncthreads();
    for (int i = threadIdx.x; i < CH * FH; i += 256) {
        int r = i / FH, f = i - r * FH;
        int node = base + r;
        if (node < n) {
            int g = batch[node];
            atomicAdd(&lp[g * FH + f], h[node * FH + f]);
            if (f == 0) atomicAdd(&lc[g], 1.0f);
        }
    }
    __syncthreads();
    for (int i = threadIdx.x; i < NG * FH; i += 256)
        if (lp[i] != 0.0f) atomicAdd(&pooled[i], lp[i]);
    if (threadIdx.x < NG)
        if (lc[threadIdx.x] != 0.0f) atomicAdd(&cnt[threadIdx.x], lc[threadIdx.x]);
}

// Kernel 8: heads — one block per graph
__global__ __launch_bounds__(128) void head_k(const float* __restrict__ pooled,
                                              const float* __restrict__ cnt,
                                              const float* __restrict__ u,
                                              const float* __restrict__ aW1, const float* __restrict__ ab1,
                                              const float* __restrict__ aW2, const float* __restrict__ ab2,
                                              const float* __restrict__ cW1, const float* __restrict__ cb1,
                                              const float* __restrict__ cW2, const float* __restrict__ cb2,
                                              float* __restrict__ out, int G) {
    int g = blockIdx.x;
    int t = threadIdx.x;
    __shared__ float comb[FH + GU];
    __shared__ float hidA[FH];
    __shared__ float hidC[FH];
    __shared__ float tmp[FH];
    float c = fmaxf(cnt[g], 1.0f);
    if (t < FH) comb[t] = pooled[g * FH + t] / c;
    else if (t < FH + GU) comb[t] = u[g * GU + (t - FH)];
    __syncthreads();
    if (t < FH) {
        float a = ab1[t], cc = cb1[t];
        for (int k = 0; k < FH + GU; k++) {
            float cv = comb[k];
            a += cv * aW1[k * FH + t];
            cc += cv * cW1[k * FH + t];
        }
        hidA[t] = fmaxf(a, 0.0f);
        hidC[t] = fmaxf(cc, 0.0f);
    }
    __syncthreads();
    if (t < GA) {
        float a = ab2[t];
        for (int j = 0; j < FH; j++) a += hidA[j] * aW2[j * GA + t];
        out[g * GA + t] = a;
    }
    if (t >= 32 && t < 32 + FH) tmp[t - 32] = hidC[t - 32] * cW2[t - 32];
    __syncthreads();
    if (t == 0) {
        float v = cb2[0];
        for (int j = 0; j < FH; j++) v += tmp[j];
        out[G * GA + g] = v;
    }
}

extern "C" void kernel_launch(void* const* d_in, const int* in_sizes, int n_in,
                              void* d_out, int out_size, void* d_ws, size_t ws_size,
                              hipStream_t stream) {
    const float* x   = (const float*)d_in[0];
    const int*   ei  = (const int*)d_in[1];
    const int*   bat = (const int*)d_in[2];
    const float* u   = (const float*)d_in[3];
    const float* W1  = (const float*)d_in[4];
    const float* b1  = (const float*)d_in[5];
    const float* W2  = (const float*)d_in[6];
    const float* b2  = (const float*)d_in[7];
    const float* aW1 = (const float*)d_in[8];
    const float* ab1 = (const float*)d_in[9];
    const float* aW2 = (const float*)d_in[10];
    const float* ab2 = (const float*)d_in[11];
    const float* cW1 = (const float*)d_in[12];
    const float* cb1 = (const float*)d_in[13];
    const float* cW2 = (const float*)d_in[14];
    const float* cb2 = (const float*)d_in[15];
    float* out = (float*)d_out;

    const int N = in_sizes[0] / FH;
    const int E = in_sizes[1] / 2;
    const int G = in_sizes[3] / GU;

    const int* src = ei;
    const int* dst = ei + E;

    // Workspace layout (4-byte units, 64-elem aligned blocks)
    float* ws = (float*)d_ws;
    size_t o = 0;
    int*   degI     = (int*)(ws + o);   o += 50048;            // N ints
    float* pooled   = ws + o;           o += NG * FH;          // 6144
    float* cnt      = ws + o;           o += 64;
    size_t zero_elems = o;                                     // zero [0, o)
    float* dis      = ws + o;           o += 50048;
    int*   rowstart = (int*)(ws + o);   o += 50048;            // N+1
    int*   cursor   = (int*)(ws + o);   o += 50048;
    int*   csr      = (int*)(ws + o);   o += 800000;           // E
    float* hXs      = ws + o;           o += (size_t)N * FH;
    float* hOut     = ws + o;           o += (size_t)N * FH;
    (void)ws_size;

    hipMemsetAsync(d_ws, 0, zero_elems * sizeof(float), stream);

    int gridE = (E + 255) / 256;
    int gridN = (N + 255) / 256;
    int gridG4 = (N * 24 + 255) / 256;
    int gridGemm = (N + 31) / 32;

    count_deg_k<<<gridE, 256, 0, stream>>>(dst, degI, E);
    dis_k<<<gridN, 256, 0, stream>>>(degI, dis, N);
    scan_k<<<1, 1024, 0, stream>>>(degI, rowstart, cursor, N);
    fill_k<<<gridE, 256, 0, stream>>>(src, dst, cursor, csr, E);

    // Layer 1
    gemm96s_k<<<gridGemm, dim3(128, 2), 0, stream>>>(x, W1, dis, hXs, N);
    gather4_k<<<gridG4, 256, 0, stream>>>(hXs, dis, rowstart, csr, b1, hOut, N);
    // Layer 2
    gemm96s_k<<<gridGemm, dim3(128, 2), 0, stream>>>(hOut, W2, dis, hXs, N);
    gather4_k<<<gridG4, 256, 0, stream>>>(hXs, dis, rowstart, csr, b2, hOut, N);

    // Pool + heads
    pool_k<<<gridN, 256, 0, stream>>>(hOut, bat, pooled, cnt, N);
    head_k<<<G, 128, 0, stream>>>(pooled, cnt, u, aW1, ab1, aW2, ab2,
                                  cW1, cb1, cW2, cb2, out, G);
}

// Round 3
// 335.200 us; speedup vs baseline: 1.7512x; 1.3140x over previous
//
#include <hip/hip_runtime.h>
#include <hip/hip_bf16.h>

// Sizes (fixed by the problem, N/E/G derived from in_sizes at launch)
#define FH 96      // F == H == 96
#define GU 32      // U
#define GA 16      // A
#define NG 64      // G

// ---------------------------------------------------------------------------
// Kernel 1: in-degree count (int atomics, exact)
__global__ void count_deg_k(const int* __restrict__ dst, int* __restrict__ deg, int E) {
    int e = blockIdx.x * blockDim.x + threadIdx.x;
    if (e < E) atomicAdd(&deg[dst[e]], 1);
}

// ---------------------------------------------------------------------------
// Multi-block exclusive scan of deg (3 stages, 1024 elems per block)
// Stage A: per-block sums
__global__ __launch_bounds__(256) void partial_k(const int* __restrict__ deg,
                                                 int* __restrict__ blockSums, int n) {
    int base = blockIdx.x * 1024;
    int t = threadIdx.x;
    int s = 0;
#pragma unroll
    for (int j = 0; j < 4; j++) {
        int i = base + t * 4 + j;
        if (i < n) s += deg[i];
    }
    __shared__ int red[4];
    for (int off = 32; off > 0; off >>= 1) s += __shfl_down(s, off, 64);
    if ((t & 63) == 0) red[t >> 6] = s;
    __syncthreads();
    if (t == 0) blockSums[blockIdx.x] = red[0] + red[1] + red[2] + red[3];
}

// Stage B: single small block scans the block sums (nb <= 256)
__global__ __launch_bounds__(256) void scanpart_k(const int* __restrict__ blockSums,
                                                  int* __restrict__ blockOff, int nb) {
    __shared__ int sh[256];
    int t = threadIdx.x;
    sh[t] = (t < nb) ? blockSums[t] : 0;
    __syncthreads();
    for (int off = 1; off < 256; off <<= 1) {
        int v = 0;
        if (t >= off) v = sh[t - off];
        __syncthreads();
        if (t >= off) sh[t] += v;
        __syncthreads();
    }
    if (t < nb) blockOff[t] = (t == 0) ? 0 : sh[t - 1];
}

// Stage C: per-block exclusive scan + global offset; writes rowstart, cursor,
// and fused dis = rsqrt(deg+1).
__global__ __launch_bounds__(256) void emit_k(const int* __restrict__ deg,
                                              const int* __restrict__ blockOff,
                                              int* __restrict__ rowstart,
                                              int* __restrict__ cursor,
                                              float* __restrict__ dis, int n) {
    __shared__ int sh[256];
    int base = blockIdx.x * 1024;
    int t = threadIdx.x;
    int d[4];
    int s = 0;
#pragma unroll
    for (int j = 0; j < 4; j++) {
        int i = base + t * 4 + j;
        d[j] = (i < n) ? deg[i] : 0;
        s += d[j];
    }
    sh[t] = s;
    __syncthreads();
    for (int off = 1; off < 256; off <<= 1) {
        int v = 0;
        if (t >= off) v = sh[t - off];
        __syncthreads();
        if (t >= off) sh[t] += v;
        __syncthreads();
    }
    int run = blockOff[blockIdx.x] + ((t == 0) ? 0 : sh[t - 1]);
#pragma unroll
    for (int j = 0; j < 4; j++) {
        int i = base + t * 4 + j;
        if (i < n) {
            rowstart[i] = run;
            cursor[i] = run;
            dis[i] = rsqrtf((float)d[j] + 1.0f);
        }
        run += d[j];
    }
    if (blockIdx.x == gridDim.x - 1 && t == 255) rowstart[n] = run;
}

// Kernel 4: fill CSR (src ids per dst)
__global__ void fill_k(const int* __restrict__ src, const int* __restrict__ dst,
                       int* __restrict__ cursor, int* __restrict__ csr, int E) {
    int e = blockIdx.x * blockDim.x + threadIdx.x;
    if (e < E) {
        int pos = atomicAdd(&cursor[dst[e]], 1);
        csr[pos] = src[e];
    }
}

// Kernel 5: Y[n][f] = (sum_k X[n][k] * W[k][f]) * scale[n]   (no bias)
// block = (128, 2); 32 rows per block; thread (fc, ty) computes 16 rows' col fc.
__global__ __launch_bounds__(256) void gemm96s_k(const float* __restrict__ X,
                                                 const float* __restrict__ W,
                                                 const float* __restrict__ scale,
                                                 float* __restrict__ Y, int nrows) {
    __shared__ float Ws[FH][100];   // padded
    __shared__ float Xs[32][100];   // padded
    int t = threadIdx.y * 128 + threadIdx.x;
    // stage W
    for (int i = t; i < FH * FH; i += 256) Ws[i / FH][i % FH] = W[i];
    // stage X tile
    int base = blockIdx.x * 32;
    for (int i = t; i < 32 * FH; i += 256) {
        int r = i / FH, c = i % FH;
        int node = base + r;
        Xs[r][c] = (node < nrows) ? X[node * FH + c] : 0.0f;
    }
    __syncthreads();

    int fc = min((int)threadIdx.x, FH - 1);
    int nb = threadIdx.y * 16;
    float acc[16];
#pragma unroll
    for (int i = 0; i < 16; i++) acc[i] = 0.0f;
    for (int kb = 0; kb < FH / 4; kb++) {
        int k = kb * 4;
        float w0 = Ws[k][fc], w1 = Ws[k + 1][fc], w2 = Ws[k + 2][fc], w3 = Ws[k + 3][fc];
#pragma unroll
        for (int i = 0; i < 16; i++) {
            const float4 xv = *(const float4*)&Xs[nb + i][k];
            acc[i] += xv.x * w0 + xv.y * w1 + xv.z * w2 + xv.w * w3;
        }
    }
    if (threadIdx.x < FH) {
#pragma unroll
        for (int i = 0; i < 16; i++) {
            int node = base + nb + i;
            if (node < nrows) Y[node * FH + threadIdx.x] = acc[i] * scale[node];
        }
    }
}

// Kernel 6: fused aggregate + self-loop + bias + relu, float4 per thread.
// hXs is pre-scaled: hXs[n][f] = (X@W)[n][f] * dis[n]
// hOut[n][f] = relu( dis[n] * ( sum_e hXs[src_e][f] + hXs[n][f] ) + b[f] )
__global__ void gather4_k(const float* __restrict__ hXs, const float* __restrict__ dis,
                          const int* __restrict__ rowstart,
                          const int* __restrict__ csr, const float* __restrict__ bias,
                          float* __restrict__ hOut, int n) {
    int idx = blockIdx.x * blockDim.x + threadIdx.x;
    if (idx >= n * 24) return;
    int node = idx / 24;
    int fq = idx - node * 24;
    int f4 = fq * 4;
    int s = rowstart[node];
    int e = rowstart[node + 1];

    float4 acc = *(const float4*)&hXs[node * FH + f4];   // self term (pre-scaled)
    int p = s;
    for (; p + 4 <= e; p += 4) {
        int i0 = csr[p], i1 = csr[p + 1], i2 = csr[p + 2], i3 = csr[p + 3];
        float4 a = *(const float4*)&hXs[i0 * FH + f4];
        float4 b = *(const float4*)&hXs[i1 * FH + f4];
        float4 c = *(const float4*)&hXs[i2 * FH + f4];
        float4 d = *(const float4*)&hXs[i3 * FH + f4];
        acc.x += (a.x + b.x) + (c.x + d.x);
        acc.y += (a.y + b.y) + (c.y + d.y);
        acc.z += (a.z + b.z) + (c.z + d.z);
        acc.w += (a.w + b.w) + (c.w + d.w);
    }
    for (; p < e; p++) {
        int i0 = csr[p];
        float4 a = *(const float4*)&hXs[i0 * FH + f4];
        acc.x += a.x; acc.y += a.y; acc.z += a.z; acc.w += a.w;
    }
    float dn = dis[node];
    const float4 bv = *(const float4*)&bias[f4];
    float4 o;
    o.x = fmaxf(acc.x * dn + bv.x, 0.0f);
    o.y = fmaxf(acc.y * dn + bv.y, 0.0f);
    o.z = fmaxf(acc.z * dn + bv.z, 0.0f);
    o.w = fmaxf(acc.w * dn + bv.w, 0.0f);
    *(float4*)&hOut[node * FH + f4] = o;
}

// Kernel 7: pooling — per-block LDS accumulation then global atomics
__global__ __launch_bounds__(256) void pool_k(const float* __restrict__ h,
                                              const int* __restrict__ batch,
                                              float* __restrict__ pooled,
                                              float* __restrict__ cnt, int n) {
    __shared__ float lp[NG * FH];
    __shared__ float lc[NG];
    const int CH = 256;
    int base = blockIdx.x * CH;
    for (int i = threadIdx.x; i < NG * FH; i += 256) lp[i] = 0.0f;
    for (int i = threadIdx.x; i < NG; i += 256) lc[i] = 0.0f;
    __syncthreads();
    for (int i = threadIdx.x; i < CH * FH; i += 256) {
        int r = i / FH, f = i - r * FH;
        int node = base + r;
        if (node < n) {
            int g = batch[node];
            atomicAdd(&lp[g * FH + f], h[node * FH + f]);
            if (f == 0) atomicAdd(&lc[g], 1.0f);
        }
    }
    __syncthreads();
    for (int i = threadIdx.x; i < NG * FH; i += 256)
        if (lp[i] != 0.0f) atomicAdd(&pooled[i], lp[i]);
    if (threadIdx.x < NG)
        if (lc[threadIdx.x] != 0.0f) atomicAdd(&cnt[threadIdx.x], lc[threadIdx.x]);
}

// Kernel 8: heads — one block per graph
__global__ __launch_bounds__(128) void head_k(const float* __restrict__ pooled,
                                              const float* __restrict__ cnt,
                                              const float* __restrict__ u,
                                              const float* __restrict__ aW1, const float* __restrict__ ab1,
                                              const float* __restrict__ aW2, const float* __restrict__ ab2,
                                              const float* __restrict__ cW1, const float* __restrict__ cb1,
                                              const float* __restrict__ cW2, const float* __restrict__ cb2,
                                              float* __restrict__ out, int G) {
    int g = blockIdx.x;
    int t = threadIdx.x;
    __shared__ float comb[FH + GU];
    __shared__ float hidA[FH];
    __shared__ float hidC[FH];
    __shared__ float tmp[FH];
    float c = fmaxf(cnt[g], 1.0f);
    if (t < FH) comb[t] = pooled[g * FH + t] / c;
    else if (t < FH + GU) comb[t] = u[g * GU + (t - FH)];
    __syncthreads();
    if (t < FH) {
        float a = ab1[t], cc = cb1[t];
        for (int k = 0; k < FH + GU; k++) {
            float cv = comb[k];
            a += cv * aW1[k * FH + t];
            cc += cv * cW1[k * FH + t];
        }
        hidA[t] = fmaxf(a, 0.0f);
        hidC[t] = fmaxf(cc, 0.0f);
    }
    __syncthreads();
    if (t < GA) {
        float a = ab2[t];
        for (int j = 0; j < FH; j++) a += hidA[j] * aW2[j * GA + t];
        out[g * GA + t] = a;
    }
    if (t >= 32 && t < 32 + FH) tmp[t - 32] = hidC[t - 32] * cW2[t - 32];
    __syncthreads();
    if (t == 0) {
        float v = cb2[0];
        for (int j = 0; j < FH; j++) v += tmp[j];
        out[G * GA + g] = v;
    }
}

extern "C" void kernel_launch(void* const* d_in, const int* in_sizes, int n_in,
                              void* d_out, int out_size, void* d_ws, size_t ws_size,
                              hipStream_t stream) {
    const float* x   = (const float*)d_in[0];
    const int*   ei  = (const int*)d_in[1];
    const int*   bat = (const int*)d_in[2];
    const float* u   = (const float*)d_in[3];
    const float* W1  = (const float*)d_in[4];
    const float* b1  = (const float*)d_in[5];
    const float* W2  = (const float*)d_in[6];
    const float* b2  = (const float*)d_in[7];
    const float* aW1 = (const float*)d_in[8];
    const float* ab1 = (const float*)d_in[9];
    const float* aW2 = (const float*)d_in[10];
    const float* ab2 = (const float*)d_in[11];
    const float* cW1 = (const float*)d_in[12];
    const float* cb1 = (const float*)d_in[13];
    const float* cW2 = (const float*)d_in[14];
    const float* cb2 = (const float*)d_in[15];
    float* out = (float*)d_out;

    const int N = in_sizes[0] / FH;
    const int E = in_sizes[1] / 2;
    const int G = in_sizes[3] / GU;

    const int* src = ei;
    const int* dst = ei + E;

    // Workspace layout (4-byte units, 64-elem aligned blocks)
    float* ws = (float*)d_ws;
    size_t o = 0;
    int*   degI     = (int*)(ws + o);   o += 50048;            // N ints
    float* pooled   = ws + o;           o += NG * FH;          // 6144
    float* cnt      = ws + o;           o += 64;
    size_t zero_elems = o;                                     // zero [0, o)
    float* dis      = ws + o;           o += 50048;
    int*   rowstart = (int*)(ws + o);   o += 50048;            // N+1
    int*   cursor   = (int*)(ws + o);   o += 50048;
    int*   blockSums= (int*)(ws + o);   o += 512;
    int*   blockOff = (int*)(ws + o);   o += 512;
    int*   csr      = (int*)(ws + o);   o += 800000;           // E
    float* hXs      = ws + o;           o += (size_t)N * FH;
    float* hOut     = ws + o;           o += (size_t)N * FH;
    (void)ws_size;

    hipMemsetAsync(d_ws, 0, zero_elems * sizeof(float), stream);

    int gridE = (E + 255) / 256;
    int gridN = (N + 255) / 256;
    int gridG4 = (N * 24 + 255) / 256;
    int gridGemm = (N + 31) / 32;
    int nbScan = (N + 1023) / 1024;

    count_deg_k<<<gridE, 256, 0, stream>>>(dst, degI, E);
    partial_k<<<nbScan, 256, 0, stream>>>(degI, blockSums, N);
    scanpart_k<<<1, 256, 0, stream>>>(blockSums, blockOff, nbScan);
    emit_k<<<nbScan, 256, 0, stream>>>(degI, blockOff, rowstart, cursor, dis, N);
    fill_k<<<gridE, 256, 0, stream>>>(src, dst, cursor, csr, E);

    // Layer 1
    gemm96s_k<<<gridGemm, dim3(128, 2), 0, stream>>>(x, W1, dis, hXs, N);
    gather4_k<<<gridG4, 256, 0, stream>>>(hXs, dis, rowstart, csr, b1, hOut, N);
    // Layer 2
    gemm96s_k<<<gridGemm, dim3(128, 2), 0, stream>>>(hOut, W2, dis, hXs, N);
    gather4_k<<<gridG4, 256, 0, stream>>>(hXs, dis, rowstart, csr, b2, hOut, N);

    // Pool + heads
    pool_k<<<gridN, 256, 0, stream>>>(hOut, bat, pooled, cnt, N);
    head_k<<<G, 128, 0, stream>>>(pooled, cnt, u, aW1, ab1, aW2, ab2,
                                  cW1, cb1, cW2, cb2, out, G);
}

// Round 4
// 269.082 us; speedup vs baseline: 2.1814x; 1.2457x over previous
//
#include <hip/hip_runtime.h>
#include <hip/hip_bf16.h>

// Sizes (fixed by the problem, N/E/G derived from in_sizes at launch)
#define FH 96      // F == H == 96
#define GU 32      // U
#define GA 16      // A
#define NG 64      // G

typedef __attribute__((ext_vector_type(8))) short bf16x8;
typedef __attribute__((ext_vector_type(4))) float f32x4;

// fp32 -> bf16 (RNE) and back, as raw bit ops
static __device__ __forceinline__ unsigned short f2bf(float f) {
    unsigned int u = __float_as_uint(f);
    unsigned int r = (u + 0x7fffu + ((u >> 16) & 1u)) >> 16;
    return (unsigned short)r;
}
static __device__ __forceinline__ float bf2f(unsigned short h) {
    return __uint_as_float(((unsigned int)h) << 16);
}

// ---------------------------------------------------------------------------
// Kernel 1: in-degree count (int atomics, exact)
__global__ void count_deg_k(const int* __restrict__ dst, int* __restrict__ deg, int E) {
    int e = blockIdx.x * blockDim.x + threadIdx.x;
    if (e < E) atomicAdd(&deg[dst[e]], 1);
}

// Multi-block exclusive scan of deg (3 stages, 1024 elems per block)
__global__ __launch_bounds__(256) void partial_k(const int* __restrict__ deg,
                                                 int* __restrict__ blockSums, int n) {
    int base = blockIdx.x * 1024;
    int t = threadIdx.x;
    int s = 0;
#pragma unroll
    for (int j = 0; j < 4; j++) {
        int i = base + t * 4 + j;
        if (i < n) s += deg[i];
    }
    __shared__ int red[4];
    for (int off = 32; off > 0; off >>= 1) s += __shfl_down(s, off, 64);
    if ((t & 63) == 0) red[t >> 6] = s;
    __syncthreads();
    if (t == 0) blockSums[blockIdx.x] = red[0] + red[1] + red[2] + red[3];
}

__global__ __launch_bounds__(256) void scanpart_k(const int* __restrict__ blockSums,
                                                  int* __restrict__ blockOff, int nb) {
    __shared__ int sh[256];
    int t = threadIdx.x;
    sh[t] = (t < nb) ? blockSums[t] : 0;
    __syncthreads();
    for (int off = 1; off < 256; off <<= 1) {
        int v = 0;
        if (t >= off) v = sh[t - off];
        __syncthreads();
        if (t >= off) sh[t] += v;
        __syncthreads();
    }
    if (t < nb) blockOff[t] = (t == 0) ? 0 : sh[t - 1];
}

// Stage C: per-block exclusive scan + global offset; writes rowstart, cursor,
// fused dis = rsqrt(deg+1). NOTE: cursor may alias deg (same-thread RAW only).
__global__ __launch_bounds__(256) void emit_k(const int* __restrict__ deg,
                                              const int* __restrict__ blockOff,
                                              int* __restrict__ rowstart,
                                              int* __restrict__ cursor,
                                              float* __restrict__ dis, int n) {
    __shared__ int sh[256];
    int base = blockIdx.x * 1024;
    int t = threadIdx.x;
    int d[4];
    int s = 0;
#pragma unroll
    for (int j = 0; j < 4; j++) {
        int i = base + t * 4 + j;
        d[j] = (i < n) ? deg[i] : 0;
        s += d[j];
    }
    sh[t] = s;
    __syncthreads();
    for (int off = 1; off < 256; off <<= 1) {
        int v = 0;
        if (t >= off) v = sh[t - off];
        __syncthreads();
        if (t >= off) sh[t] += v;
        __syncthreads();
    }
    int run = blockOff[blockIdx.x] + ((t == 0) ? 0 : sh[t - 1]);
#pragma unroll
    for (int j = 0; j < 4; j++) {
        int i = base + t * 4 + j;
        if (i < n) {
            rowstart[i] = run;
            cursor[i] = run;
            dis[i] = rsqrtf((float)d[j] + 1.0f);
        }
        run += d[j];
    }
    if (blockIdx.x == gridDim.x - 1 && t == 255) rowstart[n] = run;
}

// Kernel 4: fill CSR (src ids per dst)
__global__ void fill_k(const int* __restrict__ src, const int* __restrict__ dst,
                       int* __restrict__ cursor, int* __restrict__ csr, int E) {
    int e = blockIdx.x * blockDim.x + threadIdx.x;
    if (e < E) {
        int pos = atomicAdd(&cursor[dst[e]], 1);
        csr[pos] = src[e];
    }
}

// ---------------------------------------------------------------------------
// Prep: W -> split bf16 hi/lo, pre-swizzled into per-lane MFMA B-fragment order.
// WB[frag*512 + lane*8 + j], frag = (t*3+ks)*6 + cgAll; element W[k][n] with
// k = ks*32 + (lane>>4)*8 + j, n = cgAll*16 + (lane&15).
// (A uses the same (lane>>4, j)->k map, so any HW k-permutation cancels.)
__global__ __launch_bounds__(256) void convW_k(const float* __restrict__ W1,
                                               const float* __restrict__ W2,
                                               unsigned short* __restrict__ WB1,
                                               unsigned short* __restrict__ WB2) {
    const float* W = (blockIdx.x == 0) ? W1 : W2;
    unsigned short* WB = (blockIdx.x == 0) ? WB1 : WB2;
    for (int idx = threadIdx.x; idx < 2 * 3 * 6 * 64 * 8; idx += 256) {
        int j = idx & 7;
        int lane = (idx >> 3) & 63;
        int frag = idx >> 9;            // 0..35
        int cg = frag % 6;
        int rest = frag / 6;            // t*3 + ks
        int ks = rest % 3;
        int t = rest / 3;
        int k = ks * 32 + (lane >> 4) * 8 + j;
        int n = cg * 16 + (lane & 15);
        float w = W[k * FH + n];
        unsigned short h = f2bf(w);
        WB[idx] = (t == 0) ? h : f2bf(w - bf2f(h));
    }
}

// Prep: X fp32 -> Xh, Xl bf16 (pad rows zeroed)
__global__ void convX_k(const float* __restrict__ X,
                        unsigned short* __restrict__ Xh,
                        unsigned short* __restrict__ Xl,
                        int nElem, int nPadElem) {
    int idx = (blockIdx.x * blockDim.x + threadIdx.x) * 4;
    if (idx >= nPadElem) return;
    float4 v = make_float4(0.f, 0.f, 0.f, 0.f);
    if (idx < nElem) v = *(const float4*)&X[idx];
    ushort4 hh, ll;
    hh.x = f2bf(v.x); ll.x = f2bf(v.x - bf2f(hh.x));
    hh.y = f2bf(v.y); ll.y = f2bf(v.y - bf2f(hh.y));
    hh.z = f2bf(v.z); ll.z = f2bf(v.z - bf2f(hh.z));
    hh.w = f2bf(v.w); ll.w = f2bf(v.w - bf2f(hh.w));
    *(ushort4*)&Xh[idx] = hh;
    *(ushort4*)&Xl[idx] = ll;
}

// ---------------------------------------------------------------------------
// MFMA GEMM: Y[r][c] = (sum_k X[r][k]*W[k][c]) * scale[r], split-bf16 (3 terms).
// Block: 64 rows x 96 cols, 4 waves as 2 wave-rows x 2 wave-cols.
// Wave: 32 rows (2 rowgroups) x 48 cols (3 colgroups). No LDS.
__global__ __launch_bounds__(256, 3) void gemm_mfma_k(
    const unsigned short* __restrict__ Xh, const unsigned short* __restrict__ Xl,
    const unsigned short* __restrict__ WB, const float* __restrict__ scale,
    float* __restrict__ Y) {
    int lane = threadIdx.x & 63;
    int wid  = threadIdx.x >> 6;
    int wr = wid >> 1, wc = wid & 1;
    int row0 = blockIdx.x * 64 + wr * 32;

    // B fragments in registers for the whole kernel (18 x b128)
    bf16x8 b[2][3][3];
#pragma unroll
    for (int t = 0; t < 2; t++)
#pragma unroll
        for (int ks = 0; ks < 3; ks++)
#pragma unroll
            for (int cg = 0; cg < 3; cg++) {
                int frag = (t * 3 + ks) * 6 + wc * 3 + cg;
                b[t][ks][cg] = *(const bf16x8*)(WB + frag * 512 + lane * 8);
            }

    f32x4 acc[2][3];
#pragma unroll
    for (int rg = 0; rg < 2; rg++)
#pragma unroll
        for (int cg = 0; cg < 3; cg++) acc[rg][cg] = (f32x4){0.f, 0.f, 0.f, 0.f};

    int r0 = lane & 15;
    int kcol = (lane >> 4) * 8;
#pragma unroll
    for (int ks = 0; ks < 3; ks++) {
        bf16x8 ah[2], al[2];
#pragma unroll
        for (int rg = 0; rg < 2; rg++) {
            size_t off = (size_t)(row0 + rg * 16 + r0) * FH + ks * 32 + kcol;
            ah[rg] = *(const bf16x8*)(Xh + off);
            al[rg] = *(const bf16x8*)(Xl + off);
        }
        // term 1: Ah * Bh   (6 independent acc chains per term)
#pragma unroll
        for (int rg = 0; rg < 2; rg++)
#pragma unroll
            for (int cg = 0; cg < 3; cg++)
                acc[rg][cg] = __builtin_amdgcn_mfma_f32_16x16x32_bf16(
                    ah[rg], b[0][ks][cg], acc[rg][cg], 0, 0, 0);
        // term 2: Ah * Bl
#pragma unroll
        for (int rg = 0; rg < 2; rg++)
#pragma unroll
            for (int cg = 0; cg < 3; cg++)
                acc[rg][cg] = __builtin_amdgcn_mfma_f32_16x16x32_bf16(
                    ah[rg], b[1][ks][cg], acc[rg][cg], 0, 0, 0);
        // term 3: Al * Bh
#pragma unroll
        for (int rg = 0; rg < 2; rg++)
#pragma unroll
            for (int cg = 0; cg < 3; cg++)
                acc[rg][cg] = __builtin_amdgcn_mfma_f32_16x16x32_bf16(
                    al[rg], b[0][ks][cg], acc[rg][cg], 0, 0, 0);
    }

    // Epilogue: C/D layout col=lane&15, row=(lane>>4)*4+reg (m89-verified)
#pragma unroll
    for (int rg = 0; rg < 2; rg++) {
#pragma unroll
        for (int r = 0; r < 4; r++) {
            int row = row0 + rg * 16 + (lane >> 4) * 4 + r;
            float s = scale[row];
#pragma unroll
            for (int cg = 0; cg < 3; cg++) {
                int col = wc * 48 + cg * 16 + (lane & 15);
                Y[(size_t)row * FH + col] = acc[rg][cg][r] * s;
            }
        }
    }
}

// ---------------------------------------------------------------------------
// Gather variant A: fp32 output (layer 2)
__global__ void gather4_k(const float* __restrict__ hXs, const float* __restrict__ dis,
                          const int* __restrict__ rowstart,
                          const int* __restrict__ csr, const float* __restrict__ bias,
                          float* __restrict__ hOut, int n) {
    int idx = blockIdx.x * blockDim.x + threadIdx.x;
    if (idx >= n * 24) return;
    int node = idx / 24;
    int fq = idx - node * 24;
    int f4 = fq * 4;
    int s = rowstart[node];
    int e = rowstart[node + 1];

    float4 acc = *(const float4*)&hXs[node * FH + f4];
    int p = s;
    for (; p + 4 <= e; p += 4) {
        int i0 = csr[p], i1 = csr[p + 1], i2 = csr[p + 2], i3 = csr[p + 3];
        float4 a = *(const float4*)&hXs[i0 * FH + f4];
        float4 b = *(const float4*)&hXs[i1 * FH + f4];
        float4 c = *(const float4*)&hXs[i2 * FH + f4];
        float4 d = *(const float4*)&hXs[i3 * FH + f4];
        acc.x += (a.x + b.x) + (c.x + d.x);
        acc.y += (a.y + b.y) + (c.y + d.y);
        acc.z += (a.z + b.z) + (c.z + d.z);
        acc.w += (a.w + b.w) + (c.w + d.w);
    }
    for (; p < e; p++) {
        int i0 = csr[p];
        float4 a = *(const float4*)&hXs[i0 * FH + f4];
        acc.x += a.x; acc.y += a.y; acc.z += a.z; acc.w += a.w;
    }
    float dn = dis[node];
    const float4 bv = *(const float4*)&bias[f4];
    float4 o;
    o.x = fmaxf(acc.x * dn + bv.x, 0.0f);
    o.y = fmaxf(acc.y * dn + bv.y, 0.0f);
    o.z = fmaxf(acc.z * dn + bv.z, 0.0f);
    o.w = fmaxf(acc.w * dn + bv.w, 0.0f);
    *(float4*)&hOut[node * FH + f4] = o;
}

// Gather variant B: emits split-bf16 pair directly (layer 1 -> GEMM2 input)
__global__ void gather4b_k(const float* __restrict__ hXs, const float* __restrict__ dis,
                           const int* __restrict__ rowstart,
                           const int* __restrict__ csr, const float* __restrict__ bias,
                           unsigned short* __restrict__ outH,
                           unsigned short* __restrict__ outL, int n) {
    int idx = blockIdx.x * blockDim.x + threadIdx.x;
    if (idx >= n * 24) return;
    int node = idx / 24;
    int fq = idx - node * 24;
    int f4 = fq * 4;
    int s = rowstart[node];
    int e = rowstart[node + 1];

    float4 acc = *(const float4*)&hXs[node * FH + f4];
    int p = s;
    for (; p + 4 <= e; p += 4) {
        int i0 = csr[p], i1 = csr[p + 1], i2 = csr[p + 2], i3 = csr[p + 3];
        float4 a = *(const float4*)&hXs[i0 * FH + f4];
        float4 b = *(const float4*)&hXs[i1 * FH + f4];
        float4 c = *(const float4*)&hXs[i2 * FH + f4];
        float4 d = *(const float4*)&hXs[i3 * FH + f4];
        acc.x += (a.x + b.x) + (c.x + d.x);
        acc.y += (a.y + b.y) + (c.y + d.y);
        acc.z += (a.z + b.z) + (c.z + d.z);
        acc.w += (a.w + b.w) + (c.w + d.w);
    }
    for (; p < e; p++) {
        int i0 = csr[p];
        float4 a = *(const float4*)&hXs[i0 * FH + f4];
        acc.x += a.x; acc.y += a.y; acc.z += a.z; acc.w += a.w;
    }
    float dn = dis[node];
    const float4 bv = *(const float4*)&bias[f4];
    float4 o;
    o.x = fmaxf(acc.x * dn + bv.x, 0.0f);
    o.y = fmaxf(acc.y * dn + bv.y, 0.0f);
    o.z = fmaxf(acc.z * dn + bv.z, 0.0f);
    o.w = fmaxf(acc.w * dn + bv.w, 0.0f);
    ushort4 hh, ll;
    hh.x = f2bf(o.x); ll.x = f2bf(o.x - bf2f(hh.x));
    hh.y = f2bf(o.y); ll.y = f2bf(o.y - bf2f(hh.y));
    hh.z = f2bf(o.z); ll.z = f2bf(o.z - bf2f(hh.z));
    hh.w = f2bf(o.w); ll.w = f2bf(o.w - bf2f(hh.w));
    *(ushort4*)&outH[node * FH + f4] = hh;
    *(ushort4*)&outL[node * FH + f4] = ll;
}

// Kernel 7: pooling — per-block LDS accumulation then global atomics
__global__ __launch_bounds__(256) void pool_k(const float* __restrict__ h,
                                              const int* __restrict__ batch,
                                              float* __restrict__ pooled,
                                              float* __restrict__ cnt, int n) {
    __shared__ float lp[NG * FH];
    __shared__ float lc[NG];
    const int CH = 256;
    int base = blockIdx.x * CH;
    for (int i = threadIdx.x; i < NG * FH; i += 256) lp[i] = 0.0f;
    for (int i = threadIdx.x; i < NG; i += 256) lc[i] = 0.0f;
    __syncthreads();
    for (int i = threadIdx.x; i < CH * FH; i += 256) {
        int r = i / FH, f = i - r * FH;
        int node = base + r;
        if (node < n) {
            int g = batch[node];
            atomicAdd(&lp[g * FH + f], h[node * FH + f]);
            if (f == 0) atomicAdd(&lc[g], 1.0f);
        }
    }
    __syncthreads();
    for (int i = threadIdx.x; i < NG * FH; i += 256)
        if (lp[i] != 0.0f) atomicAdd(&pooled[i], lp[i]);
    if (threadIdx.x < NG)
        if (lc[threadIdx.x] != 0.0f) atomicAdd(&cnt[threadIdx.x], lc[threadIdx.x]);
}

// Kernel 8: heads — one block per graph
__global__ __launch_bounds__(128) void head_k(const float* __restrict__ pooled,
                                              const float* __restrict__ cnt,
                                              const float* __restrict__ u,
                                              const float* __restrict__ aW1, const float* __restrict__ ab1,
                                              const float* __restrict__ aW2, const float* __restrict__ ab2,
                                              const float* __restrict__ cW1, const float* __restrict__ cb1,
                                              const float* __restrict__ cW2, const float* __restrict__ cb2,
                                              float* __restrict__ out, int G) {
    int g = blockIdx.x;
    int t = threadIdx.x;
    __shared__ float comb[FH + GU];
    __shared__ float hidA[FH];
    __shared__ float hidC[FH];
    __shared__ float tmp[FH];
    float c = fmaxf(cnt[g], 1.0f);
    if (t < FH) comb[t] = pooled[g * FH + t] / c;
    else if (t < FH + GU) comb[t] = u[g * GU + (t - FH)];
    __syncthreads();
    if (t < FH) {
        float a = ab1[t], cc = cb1[t];
        for (int k = 0; k < FH + GU; k++) {
            float cv = comb[k];
            a += cv * aW1[k * FH + t];
            cc += cv * cW1[k * FH + t];
        }
        hidA[t] = fmaxf(a, 0.0f);
        hidC[t] = fmaxf(cc, 0.0f);
    }
    __syncthreads();
    if (t < GA) {
        float a = ab2[t];
        for (int j = 0; j < FH; j++) a += hidA[j] * aW2[j * GA + t];
        out[g * GA + t] = a;
    }
    if (t >= 32 && t < 32 + FH) tmp[t - 32] = hidC[t - 32] * cW2[t - 32];
    __syncthreads();
    if (t == 0) {
        float v = cb2[0];
        for (int j = 0; j < FH; j++) v += tmp[j];
        out[G * GA + g] = v;
    }
}

extern "C" void kernel_launch(void* const* d_in, const int* in_sizes, int n_in,
                              void* d_out, int out_size, void* d_ws, size_t ws_size,
                              hipStream_t stream) {
    const float* x   = (const float*)d_in[0];
    const int*   ei  = (const int*)d_in[1];
    const int*   bat = (const int*)d_in[2];
    const float* u   = (const float*)d_in[3];
    const float* W1  = (const float*)d_in[4];
    const float* b1  = (const float*)d_in[5];
    const float* W2  = (const float*)d_in[6];
    const float* b2  = (const float*)d_in[7];
    const float* aW1 = (const float*)d_in[8];
    const float* ab1 = (const float*)d_in[9];
    const float* aW2 = (const float*)d_in[10];
    const float* ab2 = (const float*)d_in[11];
    const float* cW1 = (const float*)d_in[12];
    const float* cb1 = (const float*)d_in[13];
    const float* cW2 = (const float*)d_in[14];
    const float* cb2 = (const float*)d_in[15];
    float* out = (float*)d_out;

    const int N = in_sizes[0] / FH;
    const int E = in_sizes[1] / 2;
    const int G = in_sizes[3] / GU;
    const int NPAD = (N + 63) / 64 * 64;   // 50048

    const int* src = ei;
    const int* dst = ei + E;

    // Workspace layout (float units)
    float* ws = (float*)d_ws;
    size_t o = 0;
    int*   degI     = (int*)(ws + o);   o += NPAD;             // also reused as cursor
    float* pooled   = ws + o;           o += NG * FH;
    float* cnt      = ws + o;           o += 64;
    size_t zero_elems = o;                                     // zero [0, o)
    float* dis      = ws + o;           o += NPAD;
    int*   rowstart = (int*)(ws + o);   o += NPAD;             // N+1
    int*   blockSums= (int*)(ws + o);   o += 512;
    int*   blockOff = (int*)(ws + o);   o += 512;
    int*   csr      = (int*)(ws + o);   o += E;
    unsigned short* WB1 = (unsigned short*)(ws + o); o += 9216;  // 18432 ushorts
    unsigned short* WB2 = (unsigned short*)(ws + o); o += 9216;
    // regionA: Xh|Xl (bf16) -> h1h|h1l (bf16) -> hOut (fp32)
    unsigned short* Xh = (unsigned short*)(ws + o);
    unsigned short* Xl = Xh + (size_t)NPAD * FH;
    float* hOutF = (float*)Xh;          o += (size_t)NPAD * FH;   // NPAD*FH floats total
    float* hXs      = ws + o;           o += (size_t)NPAD * FH;
    (void)ws_size;

    int* cursor = degI;   // alias: emit_k has per-thread RAW only; deg dead after

    hipMemsetAsync(d_ws, 0, zero_elems * sizeof(float), stream);

    int gridE = (E + 255) / 256;
    int gridN = (N + 255) / 256;
    int gridG4 = (N * 24 + 255) / 256;
    int gridMfma = NPAD / 64;
    int nbScan = (N + 1023) / 1024;
    int gridConvX = (NPAD * FH / 4 + 255) / 256;

    count_deg_k<<<gridE, 256, 0, stream>>>(dst, degI, E);
    partial_k<<<nbScan, 256, 0, stream>>>(degI, blockSums, N);
    scanpart_k<<<1, 256, 0, stream>>>(blockSums, blockOff, nbScan);
    emit_k<<<nbScan, 256, 0, stream>>>(degI, blockOff, rowstart, cursor, dis, N);
    fill_k<<<gridE, 256, 0, stream>>>(src, dst, cursor, csr, E);

    convW_k<<<2, 256, 0, stream>>>(W1, W2, WB1, WB2);
    convX_k<<<gridConvX, 256, 0, stream>>>(x, Xh, Xl, N * FH, NPAD * FH);

    // Layer 1
    gemm_mfma_k<<<gridMfma, 256, 0, stream>>>(Xh, Xl, WB1, dis, hXs);
    gather4b_k<<<gridG4, 256, 0, stream>>>(hXs, dis, rowstart, csr, b1, Xh, Xl, N);
    // Layer 2
    gemm_mfma_k<<<gridMfma, 256, 0, stream>>>(Xh, Xl, WB2, dis, hXs);
    gather4_k<<<gridG4, 256, 0, stream>>>(hXs, dis, rowstart, csr, b2, hOutF, N);

    // Pool + heads
    pool_k<<<gridN, 256, 0, stream>>>(hOutF, bat, pooled, cnt, N);
    head_k<<<G, 128, 0, stream>>>(pooled, cnt, u, aW1, ab1, aW2, ab2,
                                  cW1, cb1, cW2, cb2, out, G);
}

// Round 6
// 239.729 us; speedup vs baseline: 2.4485x; 1.1224x over previous
//
#include <hip/hip_runtime.h>
#include <hip/hip_bf16.h>

// Sizes (fixed by the problem, N/E/G derived from in_sizes at launch)
#define FH 96      // F == H == 96
#define GU 32      // U
#define GA 16      // A
#define NG 64      // G

typedef __attribute__((ext_vector_type(8))) short bf16x8;
typedef __attribute__((ext_vector_type(4))) float f32x4;

// fp32 -> bf16 (RNE) and back, as raw bit ops
static __device__ __forceinline__ unsigned short f2bf(float f) {
    unsigned int u = __float_as_uint(f);
    unsigned int r = (u + 0x7fffu + ((u >> 16) & 1u)) >> 16;
    return (unsigned short)r;
}
static __device__ __forceinline__ float bf2f(unsigned short h) {
    return __uint_as_float(((unsigned int)h) << 16);
}

// ---------------------------------------------------------------------------
// Kernel 1: in-degree count (int atomics, exact)
__global__ void count_deg_k(const int* __restrict__ dst, int* __restrict__ deg, int E) {
    int e = blockIdx.x * blockDim.x + threadIdx.x;
    if (e < E) atomicAdd(&deg[dst[e]], 1);
}

// Multi-block exclusive scan of deg (3 stages, 1024 elems per block)
__global__ __launch_bounds__(256) void partial_k(const int* __restrict__ deg,
                                                 int* __restrict__ blockSums, int n) {
    int base = blockIdx.x * 1024;
    int t = threadIdx.x;
    int s = 0;
#pragma unroll
    for (int j = 0; j < 4; j++) {
        int i = base + t * 4 + j;
        if (i < n) s += deg[i];
    }
    __shared__ int red[4];
    for (int off = 32; off > 0; off >>= 1) s += __shfl_down(s, off, 64);
    if ((t & 63) == 0) red[t >> 6] = s;
    __syncthreads();
    if (t == 0) blockSums[blockIdx.x] = red[0] + red[1] + red[2] + red[3];
}

__global__ __launch_bounds__(256) void scanpart_k(const int* __restrict__ blockSums,
                                                  int* __restrict__ blockOff, int nb) {
    __shared__ int sh[256];
    int t = threadIdx.x;
    sh[t] = (t < nb) ? blockSums[t] : 0;
    __syncthreads();
    for (int off = 1; off < 256; off <<= 1) {
        int v = 0;
        if (t >= off) v = sh[t - off];
        __syncthreads();
        if (t >= off) sh[t] += v;
        __syncthreads();
    }
    if (t < nb) blockOff[t] = (t == 0) ? 0 : sh[t - 1];
}

// Stage C: per-block exclusive scan + global offset; writes rowstart, cursor,
// fused dis = rsqrt(deg+1). NOTE: cursor may alias deg (same-thread RAW only).
__global__ __launch_bounds__(256) void emit_k(const int* __restrict__ deg,
                                              const int* __restrict__ blockOff,
                                              int* __restrict__ rowstart,
                                              int* __restrict__ cursor,
                                              float* __restrict__ dis, int n) {
    __shared__ int sh[256];
    int base = blockIdx.x * 1024;
    int t = threadIdx.x;
    int d[4];
    int s = 0;
#pragma unroll
    for (int j = 0; j < 4; j++) {
        int i = base + t * 4 + j;
        d[j] = (i < n) ? deg[i] : 0;
        s += d[j];
    }
    sh[t] = s;
    __syncthreads();
    for (int off = 1; off < 256; off <<= 1) {
        int v = 0;
        if (t >= off) v = sh[t - off];
        __syncthreads();
        if (t >= off) sh[t] += v;
        __syncthreads();
    }
    int run = blockOff[blockIdx.x] + ((t == 0) ? 0 : sh[t - 1]);
#pragma unroll
    for (int j = 0; j < 4; j++) {
        int i = base + t * 4 + j;
        if (i < n) {
            rowstart[i] = run;
            cursor[i] = run;
            dis[i] = rsqrtf((float)d[j] + 1.0f);
        }
        run += d[j];
    }
    if (blockIdx.x == gridDim.x - 1 && t == 255) rowstart[n] = run;
}

// Kernel 4: fill CSR (src ids per dst), uint16 entries (N < 65536)
__global__ void fill_k(const int* __restrict__ src, const int* __restrict__ dst,
                       int* __restrict__ cursor, unsigned short* __restrict__ csr, int E) {
    int e = blockIdx.x * blockDim.x + threadIdx.x;
    if (e < E) {
        int pos = atomicAdd(&cursor[dst[e]], 1);
        csr[pos] = (unsigned short)src[e];
    }
}

// ---------------------------------------------------------------------------
// Prep: W -> split bf16 hi/lo, pre-swizzled into per-lane MFMA B-fragment order.
__global__ __launch_bounds__(256) void convW_k(const float* __restrict__ W1,
                                               const float* __restrict__ W2,
                                               unsigned short* __restrict__ WB1,
                                               unsigned short* __restrict__ WB2) {
    const float* W = (blockIdx.x == 0) ? W1 : W2;
    unsigned short* WB = (blockIdx.x == 0) ? WB1 : WB2;
    for (int idx = threadIdx.x; idx < 2 * 3 * 6 * 64 * 8; idx += 256) {
        int j = idx & 7;
        int lane = (idx >> 3) & 63;
        int frag = idx >> 9;            // 0..35
        int cg = frag % 6;
        int rest = frag / 6;            // t*3 + ks
        int ks = rest % 3;
        int t = rest / 3;
        int k = ks * 32 + (lane >> 4) * 8 + j;
        int n = cg * 16 + (lane & 15);
        float w = W[k * FH + n];
        unsigned short h = f2bf(w);
        WB[idx] = (t == 0) ? h : f2bf(w - bf2f(h));
    }
}

// Prep: X fp32 -> Xh, Xl bf16 (pad rows zeroed)
__global__ void convX_k(const float* __restrict__ X,
                        unsigned short* __restrict__ Xh,
                        unsigned short* __restrict__ Xl,
                        int nElem, int nPadElem) {
    int idx = (blockIdx.x * blockDim.x + threadIdx.x) * 4;
    if (idx >= nPadElem) return;
    float4 v = make_float4(0.f, 0.f, 0.f, 0.f);
    if (idx < nElem) v = *(const float4*)&X[idx];
    ushort4 hh, ll;
    hh.x = f2bf(v.x); ll.x = f2bf(v.x - bf2f(hh.x));
    hh.y = f2bf(v.y); ll.y = f2bf(v.y - bf2f(hh.y));
    hh.z = f2bf(v.z); ll.z = f2bf(v.z - bf2f(hh.z));
    hh.w = f2bf(v.w); ll.w = f2bf(v.w - bf2f(hh.w));
    *(ushort4*)&Xh[idx] = hh;
    *(ushort4*)&Xl[idx] = ll;
}

// ---------------------------------------------------------------------------
// MFMA GEMM: Yb[r][c] = bf16( (sum_k X[r][k]*W[k][c]) * scale[r] ), split-bf16.
// Block: 64 rows x 96 cols, 4 waves as 2 wave-rows x 2 wave-cols. No LDS.
__global__ __launch_bounds__(256, 3) void gemm_mfma_k(
    const unsigned short* __restrict__ Xh, const unsigned short* __restrict__ Xl,
    const unsigned short* __restrict__ WB, const float* __restrict__ scale,
    unsigned short* __restrict__ Yb) {
    int lane = threadIdx.x & 63;
    int wid  = threadIdx.x >> 6;
    int wr = wid >> 1, wc = wid & 1;
    int row0 = blockIdx.x * 64 + wr * 32;

    // B fragments in registers for the whole kernel (18 x b128)
    bf16x8 b[2][3][3];
#pragma unroll
    for (int t = 0; t < 2; t++)
#pragma unroll
        for (int ks = 0; ks < 3; ks++)
#pragma unroll
            for (int cg = 0; cg < 3; cg++) {
                int frag = (t * 3 + ks) * 6 + wc * 3 + cg;
                b[t][ks][cg] = *(const bf16x8*)(WB + frag * 512 + lane * 8);
            }

    f32x4 acc[2][3];
#pragma unroll
    for (int rg = 0; rg < 2; rg++)
#pragma unroll
        for (int cg = 0; cg < 3; cg++) acc[rg][cg] = (f32x4){0.f, 0.f, 0.f, 0.f};

    int r0 = lane & 15;
    int kcol = (lane >> 4) * 8;
#pragma unroll
    for (int ks = 0; ks < 3; ks++) {
        bf16x8 ah[2], al[2];
#pragma unroll
        for (int rg = 0; rg < 2; rg++) {
            size_t off = (size_t)(row0 + rg * 16 + r0) * FH + ks * 32 + kcol;
            ah[rg] = *(const bf16x8*)(Xh + off);
            al[rg] = *(const bf16x8*)(Xl + off);
        }
#pragma unroll
        for (int rg = 0; rg < 2; rg++)
#pragma unroll
            for (int cg = 0; cg < 3; cg++)
                acc[rg][cg] = __builtin_amdgcn_mfma_f32_16x16x32_bf16(
                    ah[rg], b[0][ks][cg], acc[rg][cg], 0, 0, 0);
#pragma unroll
        for (int rg = 0; rg < 2; rg++)
#pragma unroll
            for (int cg = 0; cg < 3; cg++)
                acc[rg][cg] = __builtin_amdgcn_mfma_f32_16x16x32_bf16(
                    ah[rg], b[1][ks][cg], acc[rg][cg], 0, 0, 0);
#pragma unroll
        for (int rg = 0; rg < 2; rg++)
#pragma unroll
            for (int cg = 0; cg < 3; cg++)
                acc[rg][cg] = __builtin_amdgcn_mfma_f32_16x16x32_bf16(
                    al[rg], b[0][ks][cg], acc[rg][cg], 0, 0, 0);
    }

    // Epilogue: C/D layout col=lane&15, row=(lane>>4)*4+reg (m89-verified)
#pragma unroll
    for (int rg = 0; rg < 2; rg++) {
#pragma unroll
        for (int r = 0; r < 4; r++) {
            int row = row0 + rg * 16 + (lane >> 4) * 4 + r;
            float s = scale[row];
#pragma unroll
            for (int cg = 0; cg < 3; cg++) {
                int col = wc * 48 + cg * 16 + (lane & 15);
                Yb[(size_t)row * FH + col] = f2bf(acc[rg][cg][r] * s);
            }
        }
    }
}

// ---------------------------------------------------------------------------
// Gather from bf16 rows, strip-8 unroll, fp32 accumulate.
// MODE 0: fp32 output (layer 2 -> pool). MODE 1: split-bf16 output (-> GEMM2).
template <int MODE>
__global__ void gather16_k(const unsigned short* __restrict__ hXb,
                           const float* __restrict__ dis,
                           const int* __restrict__ rowstart,
                           const unsigned short* __restrict__ csr,
                           const float* __restrict__ bias,
                           float* __restrict__ hOut,
                           unsigned short* __restrict__ outH,
                           unsigned short* __restrict__ outL, int n) {
    int idx = blockIdx.x * blockDim.x + threadIdx.x;
    if (idx >= n * 24) return;
    int node = idx / 24;
    int fq = idx - node * 24;
    int f4 = fq * 4;
    int s = rowstart[node];
    int e = rowstart[node + 1];
    ushort4 sv = *(const ushort4*)&hXb[node * FH + f4];
    float ax = bf2f(sv.x), ay = bf2f(sv.y), az = bf2f(sv.z), aw = bf2f(sv.w);
    int p = s;
    for (; p + 8 <= e; p += 8) {
        int i0 = csr[p],     i1 = csr[p + 1], i2 = csr[p + 2], i3 = csr[p + 3];
        int i4 = csr[p + 4], i5 = csr[p + 5], i6 = csr[p + 6], i7 = csr[p + 7];
        ushort4 v0 = *(const ushort4*)&hXb[i0 * FH + f4];
        ushort4 v1 = *(const ushort4*)&hXb[i1 * FH + f4];
        ushort4 v2 = *(const ushort4*)&hXb[i2 * FH + f4];
        ushort4 v3 = *(const ushort4*)&hXb[i3 * FH + f4];
        ushort4 v4 = *(const ushort4*)&hXb[i4 * FH + f4];
        ushort4 v5 = *(const ushort4*)&hXb[i5 * FH + f4];
        ushort4 v6 = *(const ushort4*)&hXb[i6 * FH + f4];
        ushort4 v7 = *(const ushort4*)&hXb[i7 * FH + f4];
        ax += (bf2f(v0.x) + bf2f(v1.x)) + (bf2f(v2.x) + bf2f(v3.x))
            + (bf2f(v4.x) + bf2f(v5.x)) + (bf2f(v6.x) + bf2f(v7.x));
        ay += (bf2f(v0.y) + bf2f(v1.y)) + (bf2f(v2.y) + bf2f(v3.y))
            + (bf2f(v4.y) + bf2f(v5.y)) + (bf2f(v6.y) + bf2f(v7.y));
        az += (bf2f(v0.z) + bf2f(v1.z)) + (bf2f(v2.z) + bf2f(v3.z))
            + (bf2f(v4.z) + bf2f(v5.z)) + (bf2f(v6.z) + bf2f(v7.z));
        aw += (bf2f(v0.w) + bf2f(v1.w)) + (bf2f(v2.w) + bf2f(v3.w))
            + (bf2f(v4.w) + bf2f(v5.w)) + (bf2f(v6.w) + bf2f(v7.w));
    }
    for (; p < e; p++) {
        int i0 = csr[p];
        ushort4 v0 = *(const ushort4*)&hXb[i0 * FH + f4];
        ax += bf2f(v0.x); ay += bf2f(v0.y); az += bf2f(v0.z); aw += bf2f(v0.w);
    }
    float dn = dis[node];
    const float4 bv = *(const float4*)&bias[f4];
    float ox = fmaxf(ax * dn + bv.x, 0.0f);
    float oy = fmaxf(ay * dn + bv.y, 0.0f);
    float oz = fmaxf(az * dn + bv.z, 0.0f);
    float ow = fmaxf(aw * dn + bv.w, 0.0f);
    if (MODE == 0) {
        float4 o = make_float4(ox, oy, oz, ow);
        *(float4*)&hOut[node * FH + f4] = o;
    } else {
        ushort4 hh, ll;
        hh.x = f2bf(ox); ll.x = f2bf(ox - bf2f(hh.x));
        hh.y = f2bf(oy); ll.y = f2bf(oy - bf2f(hh.y));
        hh.z = f2bf(oz); ll.z = f2bf(oz - bf2f(hh.z));
        hh.w = f2bf(ow); ll.w = f2bf(ow - bf2f(hh.w));
        *(ushort4*)&outH[node * FH + f4] = hh;
        *(ushort4*)&outL[node * FH + f4] = ll;
    }
}

// Kernel 7: pooling — per-block LDS accumulation then global atomics
__global__ __launch_bounds__(256) void pool_k(const float* __restrict__ h,
                                              const int* __restrict__ batch,
                                              float* __restrict__ pooled,
                                              float* __restrict__ cnt, int n) {
    __shared__ float lp[NG * FH];
    __shared__ float lc[NG];
    const int CH = 256;
    int base = blockIdx.x * CH;
    for (int i = threadIdx.x; i < NG * FH; i += 256) lp[i] = 0.0f;
    for (int i = threadIdx.x; i < NG; i += 256) lc[i] = 0.0f;
    __syncthreads();
    for (int i = threadIdx.x; i < CH * FH; i += 256) {
        int r = i / FH, f = i - r * FH;
        int node = base + r;
        if (node < n) {
            int g = batch[node];
            atomicAdd(&lp[g * FH + f], h[node * FH + f]);
            if (f == 0) atomicAdd(&lc[g], 1.0f);
        }
    }
    __syncthreads();
    for (int i = threadIdx.x; i < NG * FH; i += 256)
        if (lp[i] != 0.0f) atomicAdd(&pooled[i], lp[i]);
    if (threadIdx.x < NG)
        if (lc[threadIdx.x] != 0.0f) atomicAdd(&cnt[threadIdx.x], lc[threadIdx.x]);
}

// Kernel 8: heads — one block per graph
__global__ __launch_bounds__(128) void head_k(const float* __restrict__ pooled,
                                              const float* __restrict__ cnt,
                                              const float* __restrict__ u,
                                              const float* __restrict__ aW1, const float* __restrict__ ab1,
                                              const float* __restrict__ aW2, const float* __restrict__ ab2,
                                              const float* __restrict__ cW1, const float* __restrict__ cb1,
                                              const float* __restrict__ cW2, const float* __restrict__ cb2,
                                              float* __restrict__ out, int G) {
    int g = blockIdx.x;
    int t = threadIdx.x;
    __shared__ float comb[FH + GU];
    __shared__ float hidA[FH];
    __shared__ float hidC[FH];
    __shared__ float tmp[FH];
    float c = fmaxf(cnt[g], 1.0f);
    if (t < FH) comb[t] = pooled[g * FH + t] / c;
    else if (t < FH + GU) comb[t] = u[g * GU + (t - FH)];
    __syncthreads();
    if (t < FH) {
        float a = ab1[t], cc = cb1[t];
        for (int k = 0; k < FH + GU; k++) {
            float cv = comb[k];
            a += cv * aW1[k * FH + t];
            cc += cv * cW1[k * FH + t];
        }
        hidA[t] = fmaxf(a, 0.0f);
        hidC[t] = fmaxf(cc, 0.0f);
    }
    __syncthreads();
    if (t < GA) {
        float a = ab2[t];
        for (int j = 0; j < FH; j++) a += hidA[j] * aW2[j * GA + t];
        out[g * GA + t] = a;
    }
    if (t >= 32 && t < 32 + FH) tmp[t - 32] = hidC[t - 32] * cW2[t - 32];
    __syncthreads();
    if (t == 0) {
        float v = cb2[0];
        for (int j = 0; j < FH; j++) v += tmp[j];
        out[G * GA + g] = v;
    }
}

extern "C" void kernel_launch(void* const* d_in, const int* in_sizes, int n_in,
                              void* d_out, int out_size, void* d_ws, size_t ws_size,
                              hipStream_t stream) {
    const float* x   = (const float*)d_in[0];
    const int*   ei  = (const int*)d_in[1];
    const int*   bat = (const int*)d_in[2];
    const float* u   = (const float*)d_in[3];
    const float* W1  = (const float*)d_in[4];
    const float* b1  = (const float*)d_in[5];
    const float* W2  = (const float*)d_in[6];
    const float* b2  = (const float*)d_in[7];
    const float* aW1 = (const float*)d_in[8];
    const float* ab1 = (const float*)d_in[9];
    const float* aW2 = (const float*)d_in[10];
    const float* ab2 = (const float*)d_in[11];
    const float* cW1 = (const float*)d_in[12];
    const float* cb1 = (const float*)d_in[13];
    const float* cW2 = (const float*)d_in[14];
    const float* cb2 = (const float*)d_in[15];
    float* out = (float*)d_out;

    const int N = in_sizes[0] / FH;
    const int E = in_sizes[1] / 2;
    const int G = in_sizes[3] / GU;
    const int NPAD = (N + 63) / 64 * 64;   // 50048

    const int* src = ei;
    const int* dst = ei + E;

    // Workspace layout (float units, 64-aligned blocks)
    float* ws = (float*)d_ws;
    size_t o = 0;
    int*   degI     = (int*)(ws + o);   o += NPAD;             // reused as cursor
    float* pooled   = ws + o;           o += NG * FH;
    float* cnt      = ws + o;           o += 64;
    size_t zero_elems = o;                                     // zero [0, o)
    float* dis      = ws + o;           o += NPAD;
    int*   rowstart = (int*)(ws + o);   o += NPAD;             // N+1
    int*   blockSums= (int*)(ws + o);   o += 512;
    int*   blockOff = (int*)(ws + o);   o += 512;
    unsigned short* csr16 = (unsigned short*)(ws + o); o += ((size_t)(E + 1) / 2 + 63) / 64 * 64;
    unsigned short* WB1 = (unsigned short*)(ws + o); o += 9216;  // 18432 ushorts
    unsigned short* WB2 = (unsigned short*)(ws + o); o += 9216;
    // regionA: Xh|Xl (bf16) -> h1h|h1l (bf16) -> hOutF (fp32)
    unsigned short* Xh = (unsigned short*)(ws + o);
    unsigned short* Xl = Xh + (size_t)NPAD * FH;
    float* hOutF = (float*)Xh;          o += (size_t)NPAD * FH;   // NPAD*FH floats
    unsigned short* hXb = (unsigned short*)(ws + o); o += (size_t)NPAD * FH / 2;
    (void)ws_size;

    int* cursor = degI;   // alias: emit_k has per-thread RAW only; deg dead after

    (void)hipMemsetAsync(d_ws, 0, zero_elems * sizeof(float), stream);

    int gridE = (E + 255) / 256;
    int gridN = (N + 255) / 256;
    int gridG4 = (N * 24 + 255) / 256;
    int gridMfma = NPAD / 64;
    int nbScan = (N + 1023) / 1024;
    int gridConvX = (NPAD * FH / 4 + 255) / 256;

    count_deg_k<<<gridE, 256, 0, stream>>>(dst, degI, E);
    partial_k<<<nbScan, 256, 0, stream>>>(degI, blockSums, N);
    scanpart_k<<<1, 256, 0, stream>>>(blockSums, blockOff, nbScan);
    emit_k<<<nbScan, 256, 0, stream>>>(degI, blockOff, rowstart, cursor, dis, N);
    fill_k<<<gridE, 256, 0, stream>>>(src, dst, cursor, csr16, E);

    convW_k<<<2, 256, 0, stream>>>(W1, W2, WB1, WB2);
    convX_k<<<gridConvX, 256, 0, stream>>>(x, Xh, Xl, N * FH, NPAD * FH);

    // Layer 1
    gemm_mfma_k<<<gridMfma, 256, 0, stream>>>(Xh, Xl, WB1, dis, hXb);
    gather16_k<1><<<gridG4, 256, 0, stream>>>(hXb, dis, rowstart, csr16, b1,
                                              (float*)nullptr, Xh, Xl, N);
    // Layer 2
    gemm_mfma_k<<<gridMfma, 256, 0, stream>>>(Xh, Xl, WB2, dis, hXb);
    gather16_k<0><<<gridG4, 256, 0, stream>>>(hXb, dis, rowstart, csr16, b2,
                                              hOutF, (unsigned short*)nullptr,
                                              (unsigned short*)nullptr, N);

    // Pool + heads
    pool_k<<<gridN, 256, 0, stream>>>(hOutF, bat, pooled, cnt, N);
    head_k<<<G, 128, 0, stream>>>(pooled, cnt, u, aW1, ab1, aW2, ab2,
                                  cW1, cb1, cW2, cb2, out, G);
}

// Round 7
// 234.974 us; speedup vs baseline: 2.4981x; 1.0202x over previous
//
#include <hip/hip_runtime.h>
#include <hip/hip_bf16.h>

// Sizes (fixed by the problem, N/E/G derived from in_sizes at launch)
#define FH 96      // F == H == 96
#define GU 32      // U
#define GA 16      // A
#define NG 64      // G

typedef __attribute__((ext_vector_type(8))) short bf16x8;
typedef __attribute__((ext_vector_type(4))) float f32x4;

// fp32 -> bf16 (RNE) and back, as raw bit ops
static __device__ __forceinline__ unsigned short f2bf(float f) {
    unsigned int u = __float_as_uint(f);
    unsigned int r = (u + 0x7fffu + ((u >> 16) & 1u)) >> 16;
    return (unsigned short)r;
}
static __device__ __forceinline__ float bf2f(unsigned short h) {
    return __uint_as_float(((unsigned int)h) << 16);
}

// ---------------------------------------------------------------------------
// Kernel 0: zero the atomic-accumulated regions (replaces slow rocclr memset)
__global__ void zero_k(float4* __restrict__ p, int n4) {
    int i = blockIdx.x * blockDim.x + threadIdx.x;
    if (i < n4) p[i] = make_float4(0.f, 0.f, 0.f, 0.f);
}

// Kernel 1: in-degree count (int atomics, exact)
__global__ void count_deg_k(const int* __restrict__ dst, int* __restrict__ deg, int E) {
    int e = blockIdx.x * blockDim.x + threadIdx.x;
    if (e < E) atomicAdd(&deg[dst[e]], 1);
}

// Multi-block exclusive scan of deg (3 stages, 1024 elems per block)
__global__ __launch_bounds__(256) void partial_k(const int* __restrict__ deg,
                                                 int* __restrict__ blockSums, int n) {
    int base = blockIdx.x * 1024;
    int t = threadIdx.x;
    int s = 0;
#pragma unroll
    for (int j = 0; j < 4; j++) {
        int i = base + t * 4 + j;
        if (i < n) s += deg[i];
    }
    __shared__ int red[4];
    for (int off = 32; off > 0; off >>= 1) s += __shfl_down(s, off, 64);
    if ((t & 63) == 0) red[t >> 6] = s;
    __syncthreads();
    if (t == 0) blockSums[blockIdx.x] = red[0] + red[1] + red[2] + red[3];
}

__global__ __launch_bounds__(256) void scanpart_k(const int* __restrict__ blockSums,
                                                  int* __restrict__ blockOff, int nb) {
    __shared__ int sh[256];
    int t = threadIdx.x;
    sh[t] = (t < nb) ? blockSums[t] : 0;
    __syncthreads();
    for (int off = 1; off < 256; off <<= 1) {
        int v = 0;
        if (t >= off) v = sh[t - off];
        __syncthreads();
        if (t >= off) sh[t] += v;
        __syncthreads();
    }
    if (t < nb) blockOff[t] = (t == 0) ? 0 : sh[t - 1];
}

// Stage C: per-block exclusive scan + global offset; writes rowstart, cursor,
// fused dis = rsqrt(deg+1). NOTE: cursor may alias deg (same-thread RAW only).
__global__ __launch_bounds__(256) void emit_k(const int* __restrict__ deg,
                                              const int* __restrict__ blockOff,
                                              int* __restrict__ rowstart,
                                              int* __restrict__ cursor,
                                              float* __restrict__ dis, int n) {
    __shared__ int sh[256];
    int base = blockIdx.x * 1024;
    int t = threadIdx.x;
    int d[4];
    int s = 0;
#pragma unroll
    for (int j = 0; j < 4; j++) {
        int i = base + t * 4 + j;
        d[j] = (i < n) ? deg[i] : 0;
        s += d[j];
    }
    sh[t] = s;
    __syncthreads();
    for (int off = 1; off < 256; off <<= 1) {
        int v = 0;
        if (t >= off) v = sh[t - off];
        __syncthreads();
        if (t >= off) sh[t] += v;
        __syncthreads();
    }
    int run = blockOff[blockIdx.x] + ((t == 0) ? 0 : sh[t - 1]);
#pragma unroll
    for (int j = 0; j < 4; j++) {
        int i = base + t * 4 + j;
        if (i < n) {
            rowstart[i] = run;
            cursor[i] = run;
            dis[i] = rsqrtf((float)d[j] + 1.0f);
        }
        run += d[j];
    }
    if (blockIdx.x == gridDim.x - 1 && t == 255) rowstart[n] = run;
}

// Kernel 4: fill CSR (src ids per dst), uint16 entries (N < 65536)
__global__ void fill_k(const int* __restrict__ src, const int* __restrict__ dst,
                       int* __restrict__ cursor, unsigned short* __restrict__ csr, int E) {
    int e = blockIdx.x * blockDim.x + threadIdx.x;
    if (e < E) {
        int pos = atomicAdd(&cursor[dst[e]], 1);
        csr[pos] = (unsigned short)src[e];
    }
}

// ---------------------------------------------------------------------------
// Prep: W -> split bf16 hi/lo, pre-swizzled into per-lane MFMA B-fragment order.
__global__ __launch_bounds__(256) void convW_k(const float* __restrict__ W1,
                                               const float* __restrict__ W2,
                                               unsigned short* __restrict__ WB1,
                                               unsigned short* __restrict__ WB2) {
    const float* W = (blockIdx.x == 0) ? W1 : W2;
    unsigned short* WB = (blockIdx.x == 0) ? WB1 : WB2;
    for (int idx = threadIdx.x; idx < 2 * 3 * 6 * 64 * 8; idx += 256) {
        int j = idx & 7;
        int lane = (idx >> 3) & 63;
        int frag = idx >> 9;            // 0..35
        int cg = frag % 6;
        int rest = frag / 6;            // t*3 + ks
        int ks = rest % 3;
        int t = rest / 3;
        int k = ks * 32 + (lane >> 4) * 8 + j;
        int n = cg * 16 + (lane & 15);
        float w = W[k * FH + n];
        unsigned short h = f2bf(w);
        WB[idx] = (t == 0) ? h : f2bf(w - bf2f(h));
    }
}

// ---------------------------------------------------------------------------
// MFMA GEMM: Yb[r][c] = bf16( (sum_k X[r][k]*W[k][c]) * scale[r] ), split-bf16.
// INMODE 0: A from fp32 Xf (convert in-register). INMODE 1: A from Xh/Xl bf16.
// Block: 64 rows x 96 cols, 4 waves as 2 wave-rows x 2 wave-cols. No LDS.
template <int INMODE>
__global__ __launch_bounds__(256, 3) void gemm_mfma_k(
    const float* __restrict__ Xf,
    const unsigned short* __restrict__ Xh, const unsigned short* __restrict__ Xl,
    const unsigned short* __restrict__ WB, const float* __restrict__ scale,
    unsigned short* __restrict__ Yb, int nrows) {
    int lane = threadIdx.x & 63;
    int wid  = threadIdx.x >> 6;
    int wr = wid >> 1, wc = wid & 1;
    int row0 = blockIdx.x * 64 + wr * 32;

    // B fragments in registers for the whole kernel (18 x b128)
    bf16x8 b[2][3][3];
#pragma unroll
    for (int t = 0; t < 2; t++)
#pragma unroll
        for (int ks = 0; ks < 3; ks++)
#pragma unroll
            for (int cg = 0; cg < 3; cg++) {
                int frag = (t * 3 + ks) * 6 + wc * 3 + cg;
                b[t][ks][cg] = *(const bf16x8*)(WB + frag * 512 + lane * 8);
            }

    f32x4 acc[2][3];
#pragma unroll
    for (int rg = 0; rg < 2; rg++)
#pragma unroll
        for (int cg = 0; cg < 3; cg++) acc[rg][cg] = (f32x4){0.f, 0.f, 0.f, 0.f};

    int r0 = lane & 15;
    int kcol = (lane >> 4) * 8;
#pragma unroll
    for (int ks = 0; ks < 3; ks++) {
        bf16x8 ah[2], al[2];
#pragma unroll
        for (int rg = 0; rg < 2; rg++) {
            if (INMODE == 1) {
                size_t off = (size_t)(row0 + rg * 16 + r0) * FH + ks * 32 + kcol;
                ah[rg] = *(const bf16x8*)(Xh + off);
                al[rg] = *(const bf16x8*)(Xl + off);
            } else {
                int rr = row0 + rg * 16 + r0;
                if (rr >= nrows) rr = nrows - 1;
                const float* xp = Xf + (size_t)rr * FH + ks * 32 + kcol;
                float4 v0 = *(const float4*)xp;
                float4 v1 = *(const float4*)(xp + 4);
                float xv[8] = {v0.x, v0.y, v0.z, v0.w, v1.x, v1.y, v1.z, v1.w};
                bf16x8 hh, ll;
#pragma unroll
                for (int j = 0; j < 8; j++) {
                    unsigned short h = f2bf(xv[j]);
                    hh[j] = (short)h;
                    ll[j] = (short)f2bf(xv[j] - bf2f(h));
                }
                ah[rg] = hh;
                al[rg] = ll;
            }
        }
#pragma unroll
        for (int rg = 0; rg < 2; rg++)
#pragma unroll
            for (int cg = 0; cg < 3; cg++)
                acc[rg][cg] = __builtin_amdgcn_mfma_f32_16x16x32_bf16(
                    ah[rg], b[0][ks][cg], acc[rg][cg], 0, 0, 0);
#pragma unroll
        for (int rg = 0; rg < 2; rg++)
#pragma unroll
            for (int cg = 0; cg < 3; cg++)
                acc[rg][cg] = __builtin_amdgcn_mfma_f32_16x16x32_bf16(
                    ah[rg], b[1][ks][cg], acc[rg][cg], 0, 0, 0);
#pragma unroll
        for (int rg = 0; rg < 2; rg++)
#pragma unroll
            for (int cg = 0; cg < 3; cg++)
                acc[rg][cg] = __builtin_amdgcn_mfma_f32_16x16x32_bf16(
                    al[rg], b[0][ks][cg], acc[rg][cg], 0, 0, 0);
    }

    // Epilogue: C/D layout col=lane&15, row=(lane>>4)*4+reg (m89-verified)
#pragma unroll
    for (int rg = 0; rg < 2; rg++) {
#pragma unroll
        for (int r = 0; r < 4; r++) {
            int row = row0 + rg * 16 + (lane >> 4) * 4 + r;
            if (row < nrows) {
                float s = scale[row];
#pragma unroll
                for (int cg = 0; cg < 3; cg++) {
                    int col = wc * 48 + cg * 16 + (lane & 15);
                    Yb[(size_t)row * FH + col] = f2bf(acc[rg][cg][r] * s);
                }
            }
        }
    }
}

// ---------------------------------------------------------------------------
// Gather from bf16 rows, strip-8 unroll, fp32 accumulate.
// MODE 0: bf16 output (layer 2 -> pool). MODE 1: split-bf16 output (-> GEMM2).
template <int MODE>
__global__ void gather16_k(const unsigned short* __restrict__ hXb,
                           const float* __restrict__ dis,
                           const int* __restrict__ rowstart,
                           const unsigned short* __restrict__ csr,
                           const float* __restrict__ bias,
                           unsigned short* __restrict__ outH,
                           unsigned short* __restrict__ outL, int n) {
    int idx = blockIdx.x * blockDim.x + threadIdx.x;
    if (idx >= n * 24) return;
    int node = idx / 24;
    int fq = idx - node * 24;
    int f4 = fq * 4;
    int s = rowstart[node];
    int e = rowstart[node + 1];
    ushort4 sv = *(const ushort4*)&hXb[node * FH + f4];
    float ax = bf2f(sv.x), ay = bf2f(sv.y), az = bf2f(sv.z), aw = bf2f(sv.w);
    int p = s;
    for (; p + 8 <= e; p += 8) {
        int i0 = csr[p],     i1 = csr[p + 1], i2 = csr[p + 2], i3 = csr[p + 3];
        int i4 = csr[p + 4], i5 = csr[p + 5], i6 = csr[p + 6], i7 = csr[p + 7];
        ushort4 v0 = *(const ushort4*)&hXb[i0 * FH + f4];
        ushort4 v1 = *(const ushort4*)&hXb[i1 * FH + f4];
        ushort4 v2 = *(const ushort4*)&hXb[i2 * FH + f4];
        ushort4 v3 = *(const ushort4*)&hXb[i3 * FH + f4];
        ushort4 v4 = *(const ushort4*)&hXb[i4 * FH + f4];
        ushort4 v5 = *(const ushort4*)&hXb[i5 * FH + f4];
        ushort4 v6 = *(const ushort4*)&hXb[i6 * FH + f4];
        ushort4 v7 = *(const ushort4*)&hXb[i7 * FH + f4];
        ax += (bf2f(v0.x) + bf2f(v1.x)) + (bf2f(v2.x) + bf2f(v3.x))
            + (bf2f(v4.x) + bf2f(v5.x)) + (bf2f(v6.x) + bf2f(v7.x));
        ay += (bf2f(v0.y) + bf2f(v1.y)) + (bf2f(v2.y) + bf2f(v3.y))
            + (bf2f(v4.y) + bf2f(v5.y)) + (bf2f(v6.y) + bf2f(v7.y));
        az += (bf2f(v0.z) + bf2f(v1.z)) + (bf2f(v2.z) + bf2f(v3.z))
            + (bf2f(v4.z) + bf2f(v5.z)) + (bf2f(v6.z) + bf2f(v7.z));
        aw += (bf2f(v0.w) + bf2f(v1.w)) + (bf2f(v2.w) + bf2f(v3.w))
            + (bf2f(v4.w) + bf2f(v5.w)) + (bf2f(v6.w) + bf2f(v7.w));
    }
    for (; p < e; p++) {
        int i0 = csr[p];
        ushort4 v0 = *(const ushort4*)&hXb[i0 * FH + f4];
        ax += bf2f(v0.x); ay += bf2f(v0.y); az += bf2f(v0.z); aw += bf2f(v0.w);
    }
    float dn = dis[node];
    const float4 bv = *(const float4*)&bias[f4];
    float ox = fmaxf(ax * dn + bv.x, 0.0f);
    float oy = fmaxf(ay * dn + bv.y, 0.0f);
    float oz = fmaxf(az * dn + bv.z, 0.0f);
    float ow = fmaxf(aw * dn + bv.w, 0.0f);
    if (MODE == 0) {
        ushort4 hh;
        hh.x = f2bf(ox); hh.y = f2bf(oy); hh.z = f2bf(oz); hh.w = f2bf(ow);
        *(ushort4*)&outH[node * FH + f4] = hh;
    } else {
        ushort4 hh, ll;
        hh.x = f2bf(ox); ll.x = f2bf(ox - bf2f(hh.x));
        hh.y = f2bf(oy); ll.y = f2bf(oy - bf2f(hh.y));
        hh.z = f2bf(oz); ll.z = f2bf(oz - bf2f(hh.z));
        hh.w = f2bf(ow); ll.w = f2bf(ow - bf2f(hh.w));
        *(ushort4*)&outH[node * FH + f4] = hh;
        *(ushort4*)&outL[node * FH + f4] = ll;
    }
}

// Kernel 7: pooling from bf16 — per-block LDS accumulation then global atomics
__global__ __launch_bounds__(256) void pool_k(const unsigned short* __restrict__ h,
                                              const int* __restrict__ batch,
                                              float* __restrict__ pooled,
                                              float* __restrict__ cnt, int n) {
    __shared__ float lp[NG * FH];
    __shared__ float lc[NG];
    const int CH = 256;
    int base = blockIdx.x * CH;
    for (int i = threadIdx.x; i < NG * FH; i += 256) lp[i] = 0.0f;
    for (int i = threadIdx.x; i < NG; i += 256) lc[i] = 0.0f;
    __syncthreads();
    for (int i = threadIdx.x; i < CH * 24; i += 256) {
        int r = i / 24, fq = i - r * 24;
        int node = base + r;
        if (node < n) {
            int g = batch[node];
            ushort4 v = *(const ushort4*)&h[node * FH + fq * 4];
            atomicAdd(&lp[g * FH + fq * 4 + 0], bf2f(v.x));
            atomicAdd(&lp[g * FH + fq * 4 + 1], bf2f(v.y));
            atomicAdd(&lp[g * FH + fq * 4 + 2], bf2f(v.z));
            atomicAdd(&lp[g * FH + fq * 4 + 3], bf2f(v.w));
            if (fq == 0) atomicAdd(&lc[g], 1.0f);
        }
    }
    __syncthreads();
    for (int i = threadIdx.x; i < NG * FH; i += 256)
        if (lp[i] != 0.0f) atomicAdd(&pooled[i], lp[i]);
    if (threadIdx.x < NG)
        if (lc[threadIdx.x] != 0.0f) atomicAdd(&cnt[threadIdx.x], lc[threadIdx.x]);
}

// Kernel 8: heads — one block per graph
__global__ __launch_bounds__(128) void head_k(const float* __restrict__ pooled,
                                              const float* __restrict__ cnt,
                                              const float* __restrict__ u,
                                              const float* __restrict__ aW1, const float* __restrict__ ab1,
                                              const float* __restrict__ aW2, const float* __restrict__ ab2,
                                              const float* __restrict__ cW1, const float* __restrict__ cb1,
                                              const float* __restrict__ cW2, const float* __restrict__ cb2,
                                              float* __restrict__ out, int G) {
    int g = blockIdx.x;
    int t = threadIdx.x;
    __shared__ float comb[FH + GU];
    __shared__ float hidA[FH];
    __shared__ float hidC[FH];
    __shared__ float tmp[FH];
    float c = fmaxf(cnt[g], 1.0f);
    if (t < FH) comb[t] = pooled[g * FH + t] / c;
    else if (t < FH + GU) comb[t] = u[g * GU + (t - FH)];
    __syncthreads();
    if (t < FH) {
        float a = ab1[t], cc = cb1[t];
        for (int k = 0; k < FH + GU; k++) {
            float cv = comb[k];
            a += cv * aW1[k * FH + t];
            cc += cv * cW1[k * FH + t];
        }
        hidA[t] = fmaxf(a, 0.0f);
        hidC[t] = fmaxf(cc, 0.0f);
    }
    __syncthreads();
    if (t < GA) {
        float a = ab2[t];
        for (int j = 0; j < FH; j++) a += hidA[j] * aW2[j * GA + t];
        out[g * GA + t] = a;
    }
    if (t >= 32 && t < 32 + FH) tmp[t - 32] = hidC[t - 32] * cW2[t - 32];
    __syncthreads();
    if (t == 0) {
        float v = cb2[0];
        for (int j = 0; j < FH; j++) v += tmp[j];
        out[G * GA + g] = v;
    }
}

extern "C" void kernel_launch(void* const* d_in, const int* in_sizes, int n_in,
                              void* d_out, int out_size, void* d_ws, size_t ws_size,
                              hipStream_t stream) {
    const float* x   = (const float*)d_in[0];
    const int*   ei  = (const int*)d_in[1];
    const int*   bat = (const int*)d_in[2];
    const float* u   = (const float*)d_in[3];
    const float* W1  = (const float*)d_in[4];
    const float* b1  = (const float*)d_in[5];
    const float* W2  = (const float*)d_in[6];
    const float* b2  = (const float*)d_in[7];
    const float* aW1 = (const float*)d_in[8];
    const float* ab1 = (const float*)d_in[9];
    const float* aW2 = (const float*)d_in[10];
    const float* ab2 = (const float*)d_in[11];
    const float* cW1 = (const float*)d_in[12];
    const float* cb1 = (const float*)d_in[13];
    const float* cW2 = (const float*)d_in[14];
    const float* cb2 = (const float*)d_in[15];
    float* out = (float*)d_out;

    const int N = in_sizes[0] / FH;
    const int E = in_sizes[1] / 2;
    const int G = in_sizes[3] / GU;
    const int NPAD = (N + 63) / 64 * 64;   // 50048

    const int* src = ei;
    const int* dst = ei + E;

    // Workspace layout (float units, 64-aligned blocks)
    float* ws = (float*)d_ws;
    size_t o = 0;
    int*   degI     = (int*)(ws + o);   o += NPAD;             // reused as cursor
    float* pooled   = ws + o;           o += NG * FH;
    float* cnt      = ws + o;           o += 64;
    size_t zero_elems = o;                                     // zero [0, o)
    float* dis      = ws + o;           o += NPAD;
    int*   rowstart = (int*)(ws + o);   o += NPAD;             // N+1
    int*   blockSums= (int*)(ws + o);   o += 512;
    int*   blockOff = (int*)(ws + o);   o += 512;
    unsigned short* csr16 = (unsigned short*)(ws + o); o += ((size_t)(E + 1) / 2 + 63) / 64 * 64;
    unsigned short* WB1 = (unsigned short*)(ws + o); o += 9216;  // 18432 ushorts
    unsigned short* WB2 = (unsigned short*)(ws + o); o += 9216;
    // regionA: Xh|Xl (bf16, written by gather1) -> h2b (bf16, gather2 out)
    unsigned short* Xh = (unsigned short*)(ws + o);
    unsigned short* Xl = Xh + (size_t)NPAD * FH;
    unsigned short* h2b = Xh;           o += (size_t)NPAD * FH;   // NPAD*FH floats
    unsigned short* hXb = (unsigned short*)(ws + o); o += (size_t)NPAD * FH / 2;
    (void)ws_size;

    int* cursor = degI;   // alias: emit_k has per-thread RAW only; deg dead after

    int gridE = (E + 255) / 256;
    int gridN = (N + 255) / 256;
    int gridG4 = (N * 24 + 255) / 256;
    int gridMfma = NPAD / 64;
    int nbScan = (N + 1023) / 1024;
    int n4zero = (int)(zero_elems / 4);
    int gridZero = (n4zero + 255) / 256;

    zero_k<<<gridZero, 256, 0, stream>>>((float4*)ws, n4zero);

    count_deg_k<<<gridE, 256, 0, stream>>>(dst, degI, E);
    partial_k<<<nbScan, 256, 0, stream>>>(degI, blockSums, N);
    scanpart_k<<<1, 256, 0, stream>>>(blockSums, blockOff, nbScan);
    emit_k<<<nbScan, 256, 0, stream>>>(degI, blockOff, rowstart, cursor, dis, N);
    fill_k<<<gridE, 256, 0, stream>>>(src, dst, cursor, csr16, E);

    convW_k<<<2, 256, 0, stream>>>(W1, W2, WB1, WB2);

    // Layer 1 (GEMM reads fp32 x directly, converts in-register)
    gemm_mfma_k<0><<<gridMfma, 256, 0, stream>>>(x, (const unsigned short*)nullptr,
                                                 (const unsigned short*)nullptr,
                                                 WB1, dis, hXb, N);
    gather16_k<1><<<gridG4, 256, 0, stream>>>(hXb, dis, rowstart, csr16, b1, Xh, Xl, N);
    // Layer 2
    gemm_mfma_k<1><<<gridMfma, 256, 0, stream>>>((const float*)nullptr, Xh, Xl,
                                                 WB2, dis, hXb, N);
    gather16_k<0><<<gridG4, 256, 0, stream>>>(hXb, dis, rowstart, csr16, b2,
                                              h2b, (unsigned short*)nullptr, N);

    // Pool + heads
    pool_k<<<gridN, 256, 0, stream>>>(h2b, bat, pooled, cnt, N);
    head_k<<<G, 128, 0, stream>>>(pooled, cnt, u, aW1, ab1, aW2, ab2,
                                  cW1, cb1, cW2, cb2, out, G);
}

// Round 8
// 200.709 us; speedup vs baseline: 2.9246x; 1.1707x over previous
//
#include <hip/hip_runtime.h>
#include <hip/hip_bf16.h>

// Sizes (fixed by the problem, N/E/G derived from in_sizes at launch)
#define FH 96      // F == H == 96
#define GU 32      // U
#define GA 16      // A
#define NG 64      // G

typedef __attribute__((ext_vector_type(8))) short bf16x8;
typedef __attribute__((ext_vector_type(8))) unsigned short u16x8;
typedef __attribute__((ext_vector_type(4))) float f32x4;

// fp32 -> bf16 (RNE) and back, as raw bit ops
static __device__ __forceinline__ unsigned short f2bf(float f) {
    unsigned int u = __float_as_uint(f);
    unsigned int r = (u + 0x7fffu + ((u >> 16) & 1u)) >> 16;
    return (unsigned short)r;
}
static __device__ __forceinline__ float bf2f(unsigned short h) {
    return __uint_as_float(((unsigned int)h) << 16);
}

// ---------------------------------------------------------------------------
// Kernel 0: zero the atomic-accumulated regions (replaces slow rocclr memset)
__global__ void zero_k(float4* __restrict__ p, int n4) {
    int i = blockIdx.x * blockDim.x + threadIdx.x;
    if (i < n4) p[i] = make_float4(0.f, 0.f, 0.f, 0.f);
}

// Kernel 1: in-degree count + per-edge rank (int atomics, exact)
__global__ void count_deg_k(const int* __restrict__ dst, int* __restrict__ deg,
                            unsigned short* __restrict__ rank16, int E) {
    int e = blockIdx.x * blockDim.x + threadIdx.x;
    if (e < E) rank16[e] = (unsigned short)atomicAdd(&deg[dst[e]], 1);
}

// Multi-block exclusive scan of deg (3 stages, 1024 elems per block)
__global__ __launch_bounds__(256) void partial_k(const int* __restrict__ deg,
                                                 int* __restrict__ blockSums, int n) {
    int base = blockIdx.x * 1024;
    int t = threadIdx.x;
    int s = 0;
#pragma unroll
    for (int j = 0; j < 4; j++) {
        int i = base + t * 4 + j;
        if (i < n) s += deg[i];
    }
    __shared__ int red[4];
    for (int off = 32; off > 0; off >>= 1) s += __shfl_down(s, off, 64);
    if ((t & 63) == 0) red[t >> 6] = s;
    __syncthreads();
    if (t == 0) blockSums[blockIdx.x] = red[0] + red[1] + red[2] + red[3];
}

__global__ __launch_bounds__(256) void scanpart_k(const int* __restrict__ blockSums,
                                                  int* __restrict__ blockOff, int nb) {
    __shared__ int sh[256];
    int t = threadIdx.x;
    sh[t] = (t < nb) ? blockSums[t] : 0;
    __syncthreads();
    for (int off = 1; off < 256; off <<= 1) {
        int v = 0;
        if (t >= off) v = sh[t - off];
        __syncthreads();
        if (t >= off) sh[t] += v;
        __syncthreads();
    }
    if (t < nb) blockOff[t] = (t == 0) ? 0 : sh[t - 1];
}

// Stage C: per-block exclusive scan + global offset; writes rowstart and
// fused dis = rsqrt(deg+1).
__global__ __launch_bounds__(256) void emit_k(const int* __restrict__ deg,
                                              const int* __restrict__ blockOff,
                                              int* __restrict__ rowstart,
                                              float* __restrict__ dis, int n) {
    __shared__ int sh[256];
    int base = blockIdx.x * 1024;
    int t = threadIdx.x;
    int d[4];
    int s = 0;
#pragma unroll
    for (int j = 0; j < 4; j++) {
        int i = base + t * 4 + j;
        d[j] = (i < n) ? deg[i] : 0;
        s += d[j];
    }
    sh[t] = s;
    __syncthreads();
    for (int off = 1; off < 256; off <<= 1) {
        int v = 0;
        if (t >= off) v = sh[t - off];
        __syncthreads();
        if (t >= off) sh[t] += v;
        __syncthreads();
    }
    int run = blockOff[blockIdx.x] + ((t == 0) ? 0 : sh[t - 1]);
#pragma unroll
    for (int j = 0; j < 4; j++) {
        int i = base + t * 4 + j;
        if (i < n) {
            rowstart[i] = run;
            dis[i] = rsqrtf((float)d[j] + 1.0f);
        }
        run += d[j];
    }
    if (blockIdx.x == gridDim.x - 1 && t == 255) rowstart[n] = run;
}

// Kernel 4: fill CSR — atomic-free (rank precomputed), uint16 entries
__global__ void fill_k(const int* __restrict__ src, const int* __restrict__ dst,
                       const int* __restrict__ rowstart,
                       const unsigned short* __restrict__ rank16,
                       unsigned short* __restrict__ csr, int E) {
    int e = blockIdx.x * blockDim.x + threadIdx.x;
    if (e < E) {
        int pos = rowstart[dst[e]] + (int)rank16[e];
        csr[pos] = (unsigned short)src[e];
    }
}

// ---------------------------------------------------------------------------
// Prep: W -> split bf16 hi/lo, pre-swizzled into per-lane MFMA B-fragment order.
__global__ __launch_bounds__(256) void convW_k(const float* __restrict__ W1,
                                               const float* __restrict__ W2,
                                               unsigned short* __restrict__ WB1,
                                               unsigned short* __restrict__ WB2) {
    const float* W = (blockIdx.x == 0) ? W1 : W2;
    unsigned short* WB = (blockIdx.x == 0) ? WB1 : WB2;
    for (int idx = threadIdx.x; idx < 2 * 3 * 6 * 64 * 8; idx += 256) {
        int j = idx & 7;
        int lane = (idx >> 3) & 63;
        int frag = idx >> 9;            // 0..35
        int cg = frag % 6;
        int rest = frag / 6;            // t*3 + ks
        int ks = rest % 3;
        int t = rest / 3;
        int k = ks * 32 + (lane >> 4) * 8 + j;
        int n = cg * 16 + (lane & 15);
        float w = W[k * FH + n];
        unsigned short h = f2bf(w);
        WB[idx] = (t == 0) ? h : f2bf(w - bf2f(h));
    }
}

// ---------------------------------------------------------------------------
// MFMA GEMM: Yb[r][c] = bf16( (sum_k X[r][k]*W[k][c]) * scale[r] ), split-bf16.
// INMODE 0: A from fp32 Xf (convert in-register). INMODE 1: A from Xh/Xl bf16.
// Block: 64 rows x 96 cols, 4 waves as 2 wave-rows x 2 wave-cols. No LDS.
template <int INMODE>
__global__ __launch_bounds__(256, 3) void gemm_mfma_k(
    const float* __restrict__ Xf,
    const unsigned short* __restrict__ Xh, const unsigned short* __restrict__ Xl,
    const unsigned short* __restrict__ WB, const float* __restrict__ scale,
    unsigned short* __restrict__ Yb, int nrows) {
    int lane = threadIdx.x & 63;
    int wid  = threadIdx.x >> 6;
    int wr = wid >> 1, wc = wid & 1;
    int row0 = blockIdx.x * 64 + wr * 32;

    // B fragments in registers for the whole kernel (18 x b128)
    bf16x8 b[2][3][3];
#pragma unroll
    for (int t = 0; t < 2; t++)
#pragma unroll
        for (int ks = 0; ks < 3; ks++)
#pragma unroll
            for (int cg = 0; cg < 3; cg++) {
                int frag = (t * 3 + ks) * 6 + wc * 3 + cg;
                b[t][ks][cg] = *(const bf16x8*)(WB + frag * 512 + lane * 8);
            }

    f32x4 acc[2][3];
#pragma unroll
    for (int rg = 0; rg < 2; rg++)
#pragma unroll
        for (int cg = 0; cg < 3; cg++) acc[rg][cg] = (f32x4){0.f, 0.f, 0.f, 0.f};

    int r0 = lane & 15;
    int kcol = (lane >> 4) * 8;
#pragma unroll
    for (int ks = 0; ks < 3; ks++) {
        bf16x8 ah[2], al[2];
#pragma unroll
        for (int rg = 0; rg < 2; rg++) {
            if (INMODE == 1) {
                size_t off = (size_t)(row0 + rg * 16 + r0) * FH + ks * 32 + kcol;
                ah[rg] = *(const bf16x8*)(Xh + off);
                al[rg] = *(const bf16x8*)(Xl + off);
            } else {
                int rr = row0 + rg * 16 + r0;
                if (rr >= nrows) rr = nrows - 1;
                const float* xp = Xf + (size_t)rr * FH + ks * 32 + kcol;
                float4 v0 = *(const float4*)xp;
                float4 v1 = *(const float4*)(xp + 4);
                float xv[8] = {v0.x, v0.y, v0.z, v0.w, v1.x, v1.y, v1.z, v1.w};
                bf16x8 hh, ll;
#pragma unroll
                for (int j = 0; j < 8; j++) {
                    unsigned short h = f2bf(xv[j]);
                    hh[j] = (short)h;
                    ll[j] = (short)f2bf(xv[j] - bf2f(h));
                }
                ah[rg] = hh;
                al[rg] = ll;
            }
        }
#pragma unroll
        for (int rg = 0; rg < 2; rg++)
#pragma unroll
            for (int cg = 0; cg < 3; cg++)
                acc[rg][cg] = __builtin_amdgcn_mfma_f32_16x16x32_bf16(
                    ah[rg], b[0][ks][cg], acc[rg][cg], 0, 0, 0);
#pragma unroll
        for (int rg = 0; rg < 2; rg++)
#pragma unroll
            for (int cg = 0; cg < 3; cg++)
                acc[rg][cg] = __builtin_amdgcn_mfma_f32_16x16x32_bf16(
                    ah[rg], b[1][ks][cg], acc[rg][cg], 0, 0, 0);
#pragma unroll
        for (int rg = 0; rg < 2; rg++)
#pragma unroll
            for (int cg = 0; cg < 3; cg++)
                acc[rg][cg] = __builtin_amdgcn_mfma_f32_16x16x32_bf16(
                    al[rg], b[0][ks][cg], acc[rg][cg], 0, 0, 0);
    }

    // Epilogue: C/D layout col=lane&15, row=(lane>>4)*4+reg (m89-verified)
#pragma unroll
    for (int rg = 0; rg < 2; rg++) {
#pragma unroll
        for (int r = 0; r < 4; r++) {
            int row = row0 + rg * 16 + (lane >> 4) * 4 + r;
            if (row < nrows) {
                float s = scale[row];
#pragma unroll
                for (int cg = 0; cg < 3; cg++) {
                    int col = wc * 48 + cg * 16 + (lane & 15);
                    Yb[(size_t)row * FH + col] = f2bf(acc[rg][cg][r] * s);
                }
            }
        }
    }
}

// ---------------------------------------------------------------------------
// Gather core: 12 threads/node, ushort8 (16B) loads, strip-4, fp32 accumulate.
static __device__ __forceinline__ void gather_core(
    const unsigned short* __restrict__ hXb, const float* __restrict__ dis,
    const int* __restrict__ rowstart, const unsigned short* __restrict__ csr,
    const float* __restrict__ bias, int node, int f8, float o[8]) {
    int s = rowstart[node];
    int e = rowstart[node + 1];
    u16x8 sv = *(const u16x8*)&hXb[node * FH + f8];
    float a[8];
#pragma unroll
    for (int j = 0; j < 8; j++) a[j] = bf2f((unsigned short)sv[j]);
    int p = s;
    for (; p + 4 <= e; p += 4) {
        int i0 = csr[p], i1 = csr[p + 1], i2 = csr[p + 2], i3 = csr[p + 3];
        u16x8 v0 = *(const u16x8*)&hXb[i0 * FH + f8];
        u16x8 v1 = *(const u16x8*)&hXb[i1 * FH + f8];
        u16x8 v2 = *(const u16x8*)&hXb[i2 * FH + f8];
        u16x8 v3 = *(const u16x8*)&hXb[i3 * FH + f8];
#pragma unroll
        for (int j = 0; j < 8; j++) {
            a[j] += (bf2f((unsigned short)v0[j]) + bf2f((unsigned short)v1[j]))
                  + (bf2f((unsigned short)v2[j]) + bf2f((unsigned short)v3[j]));
        }
    }
    for (; p < e; p++) {
        int i0 = csr[p];
        u16x8 v0 = *(const u16x8*)&hXb[i0 * FH + f8];
#pragma unroll
        for (int j = 0; j < 8; j++) a[j] += bf2f((unsigned short)v0[j]);
    }
    float dn = dis[node];
    float4 bv0 = *(const float4*)&bias[f8];
    float4 bv1 = *(const float4*)&bias[f8 + 4];
    float bb[8] = {bv0.x, bv0.y, bv0.z, bv0.w, bv1.x, bv1.y, bv1.z, bv1.w};
#pragma unroll
    for (int j = 0; j < 8; j++) o[j] = fmaxf(a[j] * dn + bb[j], 0.0f);
}

// Layer-1 gather: emits split-bf16 (hi/lo) for GEMM2
__global__ __launch_bounds__(256) void gather12a_k(
    const unsigned short* __restrict__ hXb, const float* __restrict__ dis,
    const int* __restrict__ rowstart, const unsigned short* __restrict__ csr,
    const float* __restrict__ bias, unsigned short* __restrict__ outH,
    unsigned short* __restrict__ outL, int n) {
    int idx = blockIdx.x * blockDim.x + threadIdx.x;
    if (idx >= n * 12) return;
    int node = idx / 12;
    int f8 = (idx - node * 12) * 8;
    float o[8];
    gather_core(hXb, dis, rowstart, csr, bias, node, f8, o);
    u16x8 hh, ll;
#pragma unroll
    for (int j = 0; j < 8; j++) {
        unsigned short h = f2bf(o[j]);
        hh[j] = h;
        ll[j] = f2bf(o[j] - bf2f(h));
    }
    *(u16x8*)&outH[node * FH + f8] = hh;
    *(u16x8*)&outL[node * FH + f8] = ll;
}

// Layer-2 gather fused with mean-pool accumulation (LDS privatized)
__global__ __launch_bounds__(256) void gather12p_k(
    const unsigned short* __restrict__ hXb, const float* __restrict__ dis,
    const int* __restrict__ rowstart, const unsigned short* __restrict__ csr,
    const float* __restrict__ bias, const int* __restrict__ batch,
    float* __restrict__ pooled, float* __restrict__ cnt, int n) {
    __shared__ float lp[NG * FH];
    __shared__ float lc[NG];
    for (int i = threadIdx.x; i < NG * FH; i += 256) lp[i] = 0.0f;
    if (threadIdx.x < NG) lc[threadIdx.x] = 0.0f;
    __syncthreads();

    int idx = blockIdx.x * blockDim.x + threadIdx.x;
    bool active = (idx < n * 12);
    int node = 0, f8 = 0, fq = 0;
    if (active) {
        node = idx / 12;
        fq = idx - node * 12;
        f8 = fq * 8;
        float o[8];
        gather_core(hXb, dis, rowstart, csr, bias, node, f8, o);
        int g = batch[node];
#pragma unroll
        for (int j = 0; j < 8; j++) atomicAdd(&lp[g * FH + f8 + j], o[j]);
        if (fq == 0) atomicAdd(&lc[g], 1.0f);
    }
    __syncthreads();
    for (int i = threadIdx.x; i < NG * FH; i += 256)
        if (lp[i] != 0.0f) atomicAdd(&pooled[i], lp[i]);
    if (threadIdx.x < NG)
        if (lc[threadIdx.x] != 0.0f) atomicAdd(&cnt[threadIdx.x], lc[threadIdx.x]);
}

// Kernel 8: heads — one block per graph
__global__ __launch_bounds__(128) void head_k(const float* __restrict__ pooled,
                                              const float* __restrict__ cnt,
                                              const float* __restrict__ u,
                                              const float* __restrict__ aW1, const float* __restrict__ ab1,
                                              const float* __restrict__ aW2, const float* __restrict__ ab2,
                                              const float* __restrict__ cW1, const float* __restrict__ cb1,
                                              const float* __restrict__ cW2, const float* __restrict__ cb2,
                                              float* __restrict__ out, int G) {
    int g = blockIdx.x;
    int t = threadIdx.x;
    __shared__ float comb[FH + GU];
    __shared__ float hidA[FH];
    __shared__ float hidC[FH];
    __shared__ float tmp[FH];
    float c = fmaxf(cnt[g], 1.0f);
    if (t < FH) comb[t] = pooled[g * FH + t] / c;
    else if (t < FH + GU) comb[t] = u[g * GU + (t - FH)];
    __syncthreads();
    if (t < FH) {
        float a = ab1[t], cc = cb1[t];
        for (int k = 0; k < FH + GU; k++) {
            float cv = comb[k];
            a += cv * aW1[k * FH + t];
            cc += cv * cW1[k * FH + t];
        }
        hidA[t] = fmaxf(a, 0.0f);
        hidC[t] = fmaxf(cc, 0.0f);
    }
    __syncthreads();
    if (t < GA) {
        float a = ab2[t];
        for (int j = 0; j < FH; j++) a += hidA[j] * aW2[j * GA + t];
        out[g * GA + t] = a;
    }
    if (t >= 32 && t < 32 + FH) tmp[t - 32] = hidC[t - 32] * cW2[t - 32];
    __syncthreads();
    if (t == 0) {
        float v = cb2[0];
        for (int j = 0; j < FH; j++) v += tmp[j];
        out[G * GA + g] = v;
    }
}

extern "C" void kernel_launch(void* const* d_in, const int* in_sizes, int n_in,
                              void* d_out, int out_size, void* d_ws, size_t ws_size,
                              hipStream_t stream) {
    const float* x   = (const float*)d_in[0];
    const int*   ei  = (const int*)d_in[1];
    const int*   bat = (const int*)d_in[2];
    const float* u   = (const float*)d_in[3];
    const float* W1  = (const float*)d_in[4];
    const float* b1  = (const float*)d_in[5];
    const float* W2  = (const float*)d_in[6];
    const float* b2  = (const float*)d_in[7];
    const float* aW1 = (const float*)d_in[8];
    const float* ab1 = (const float*)d_in[9];
    const float* aW2 = (const float*)d_in[10];
    const float* ab2 = (const float*)d_in[11];
    const float* cW1 = (const float*)d_in[12];
    const float* cb1 = (const float*)d_in[13];
    const float* cW2 = (const float*)d_in[14];
    const float* cb2 = (const float*)d_in[15];
    float* out = (float*)d_out;

    const int N = in_sizes[0] / FH;
    const int E = in_sizes[1] / 2;
    const int G = in_sizes[3] / GU;
    const int NPAD = (N + 63) / 64 * 64;   // 50048

    const int* src = ei;
    const int* dst = ei + E;

    // Workspace layout (float units, 64-aligned blocks)
    float* ws = (float*)d_ws;
    size_t o = 0;
    int*   degI     = (int*)(ws + o);   o += NPAD;
    float* pooled   = ws + o;           o += NG * FH;
    float* cnt      = ws + o;           o += 64;
    size_t zero_elems = o;                                     // zero [0, o)
    float* dis      = ws + o;           o += NPAD;
    int*   rowstart = (int*)(ws + o);   o += NPAD;             // N+1
    int*   blockSums= (int*)(ws + o);   o += 512;
    int*   blockOff = (int*)(ws + o);   o += 512;
    unsigned short* rank16 = (unsigned short*)(ws + o); o += ((size_t)(E + 1) / 2 + 63) / 64 * 64;
    unsigned short* csr16  = (unsigned short*)(ws + o); o += ((size_t)(E + 1) / 2 + 63) / 64 * 64;
    unsigned short* WB1 = (unsigned short*)(ws + o); o += 9216;  // 18432 ushorts
    unsigned short* WB2 = (unsigned short*)(ws + o); o += 9216;
    unsigned short* Xh = (unsigned short*)(ws + o);
    unsigned short* Xl = Xh + (size_t)NPAD * FH;
    o += (size_t)NPAD * FH;                                    // Xh|Xl (bf16 pair)
    unsigned short* hXb = (unsigned short*)(ws + o); o += (size_t)NPAD * FH / 2;
    (void)ws_size;

    int gridE = (E + 255) / 256;
    int gridG12 = (N * 12 + 255) / 256;
    int gridMfma = NPAD / 64;
    int nbScan = (N + 1023) / 1024;
    int n4zero = (int)(zero_elems / 4);
    int gridZero = (n4zero + 255) / 256;

    zero_k<<<gridZero, 256, 0, stream>>>((float4*)ws, n4zero);

    count_deg_k<<<gridE, 256, 0, stream>>>(dst, degI, rank16, E);
    partial_k<<<nbScan, 256, 0, stream>>>(degI, blockSums, N);
    scanpart_k<<<1, 256, 0, stream>>>(blockSums, blockOff, nbScan);
    emit_k<<<nbScan, 256, 0, stream>>>(degI, blockOff, rowstart, dis, N);
    fill_k<<<gridE, 256, 0, stream>>>(src, dst, rowstart, rank16, csr16, E);

    convW_k<<<2, 256, 0, stream>>>(W1, W2, WB1, WB2);

    // Layer 1 (GEMM reads fp32 x directly, converts in-register)
    gemm_mfma_k<0><<<gridMfma, 256, 0, stream>>>(x, (const unsigned short*)nullptr,
                                                 (const unsigned short*)nullptr,
                                                 WB1, dis, hXb, N);
    gather12a_k<<<gridG12, 256, 0, stream>>>(hXb, dis, rowstart, csr16, b1, Xh, Xl, N);
    // Layer 2
    gemm_mfma_k<1><<<gridMfma, 256, 0, stream>>>((const float*)nullptr, Xh, Xl,
                                                 WB2, dis, hXb, N);
    // Gather + pool fused
    gather12p_k<<<gridG12, 256, 0, stream>>>(hXb, dis, rowstart, csr16, b2,
                                             bat, pooled, cnt, N);

    head_k<<<G, 128, 0, stream>>>(pooled, cnt, u, aW1, ab1, aW2, ab2,
                                  cW1, cb1, cW2, cb2, out, G);
}